// Round 12
// baseline (641.563 us; speedup 1.0000x reference)
//
#include <hip/hip_runtime.h>
#include <hip/hip_bf16.h>

#define NN 50000
#define NE 800000
#define NET (NE + NN)
#define SCAN_NB ((NN + 255) / 256)   // 196

static inline int imin(int a, int b) { return a < b ? a : b; }

typedef _Float16 half8 __attribute__((ext_vector_type(8)));
typedef _Float16 half2v __attribute__((ext_vector_type(2)));
typedef float f32x4 __attribute__((ext_vector_type(4)));

// ---------------- CSR build (graph constant across layers) ----------------
__global__ void k_count(const int* __restrict__ edst, int* __restrict__ counts) {
    int e = blockIdx.x * blockDim.x + threadIdx.x;
    if (e >= NET) return;
    int d = (e < NE) ? edst[e] : (e - NE);   // self loops appended
    atomicAdd(&counts[d], 1);
}

__global__ __launch_bounds__(256) void k_scan1(const int* __restrict__ counts,
                                               int* __restrict__ part) {
    __shared__ int s[256];
    int t = threadIdx.x, i = blockIdx.x * 256 + t;
    s[t] = (i < NN) ? counts[i] : 0;
    __syncthreads();
    for (int off = 128; off > 0; off >>= 1) {
        if (t < off) s[t] += s[t + off];
        __syncthreads();
    }
    if (t == 0) part[blockIdx.x] = s[0];
}

__global__ __launch_bounds__(256) void k_scan2(int* __restrict__ part, int* __restrict__ offs) {
    __shared__ int s[256];
    int t = threadIdx.x;
    int v = (t < SCAN_NB) ? part[t] : 0;
    s[t] = v;
    __syncthreads();
    for (int off = 1; off < 256; off <<= 1) {
        int a = (t >= off) ? s[t - off] : 0;
        __syncthreads();
        s[t] += a;
        __syncthreads();
    }
    if (t < SCAN_NB) part[t] = s[t] - v;     // exclusive block offsets
    if (t == 255) offs[NN] = s[255];         // total (= NET)
}

__global__ __launch_bounds__(256) void k_scan3(const int* __restrict__ counts,
                                               const int* __restrict__ part,
                                               int* __restrict__ offs, int* __restrict__ cursor) {
    __shared__ int s[256];
    int t = threadIdx.x, i = blockIdx.x * 256 + t;
    int v = (i < NN) ? counts[i] : 0;
    s[t] = v;
    __syncthreads();
    for (int off = 1; off < 256; off <<= 1) {
        int a = (t >= off) ? s[t - off] : 0;
        __syncthreads();
        s[t] += a;
        __syncthreads();
    }
    if (i < NN) {
        int e = part[blockIdx.x] + s[t] - v;
        offs[i] = e;
        cursor[i] = e;
    }
}

__global__ void k_scatter(const int* __restrict__ esrc, const int* __restrict__ edst,
                          int* __restrict__ cursor, int* __restrict__ csr_src) {
    int e = blockIdx.x * blockDim.x + threadIdx.x;
    if (e >= NET) return;
    int s, d;
    if (e < NE) { s = esrc[e]; d = edst[e]; } else { s = e - NE; d = s; }
    int pos = atomicAdd(&cursor[d], 1);
    csr_src[pos] = s;
}

// ---------------- split fp32 -> f16 hi/lo pair ----------------
__global__ void k_split(const float* __restrict__ in, _Float16* __restrict__ hi,
                        _Float16* __restrict__ lo, int n) {
    int i = blockIdx.x * blockDim.x + threadIdx.x;
    int st = gridDim.x * blockDim.x;
    for (; i < n; i += st) {
        float v = in[i];
        _Float16 h = (_Float16)v;
        hi[i] = h;
        lo[i] = (_Float16)(v - (float)h);
    }
}

// ---------------- transpose + split weights: W[K][N] -> T[N][K] hi/lo (LDS-tiled) ----
__global__ __launch_bounds__(256) void k_prepw(const float* __restrict__ W,
                                               _Float16* __restrict__ Th,
                                               _Float16* __restrict__ Tl, int K, int N) {
    __shared__ float tile[32][33];
    int tx = threadIdx.x & 31, ty = threadIdx.x >> 5;
    int n0 = blockIdx.x * 32, k0 = blockIdx.y * 32;
    #pragma unroll
    for (int r = ty; r < 32; r += 8)
        tile[r][tx] = W[(size_t)(k0 + r) * N + n0 + tx];   // coalesced read
    __syncthreads();
    #pragma unroll
    for (int r = ty; r < 32; r += 8) {
        int n = n0 + r, k = k0 + tx;
        float v = tile[tx][r];
        _Float16 h = (_Float16)v;
        Th[(size_t)n * K + k] = h;                          // coalesced 64B segments
        Tl[(size_t)n * K + k] = (_Float16)(v - (float)h);
    }
}

// ---------------- fused segment-softmax + aggregate + bias + leaky ----------------
// R17: hbuf f16 (gather 435->218 MB/layer; absmax unchanged -> free).
__global__ void k_aggregate(const _Float16* __restrict__ h, const float* __restrict__ s_src,
                            const float* __restrict__ s_dst, const int* __restrict__ offs,
                            const int* __restrict__ csr_src, const float* __restrict__ bias,
                            _Float16* __restrict__ xh, _Float16* __restrict__ xl) {
    int node = blockIdx.x * 4 + (threadIdx.x >> 6);
    int lane = threadIdx.x & 63;
    if (node >= NN) return;
    int p = offs[node], pe = offs[node + 1];
    float sd = s_dst[node];
    float den = 0.f, acc0 = 0.f, acc1 = 0.f;
    for (; p + 4 <= pe; p += 4) {
        int s0 = csr_src[p + 0], s1 = csr_src[p + 1];
        int s2 = csr_src[p + 2], s3 = csr_src[p + 3];
        float e0 = s_src[s0] + sd, e1 = s_src[s1] + sd;
        float e2 = s_src[s2] + sd, e3 = s_src[s3] + sd;
        half2v a0 = *((const half2v*)(h + (size_t)s0 * 128) + lane);
        half2v a1 = *((const half2v*)(h + (size_t)s1 * 128) + lane);
        half2v a2 = *((const half2v*)(h + (size_t)s2 * 128) + lane);
        half2v a3 = *((const half2v*)(h + (size_t)s3 * 128) + lane);
        e0 = (e0 > 0.f) ? e0 : 0.2f * e0;  float w0 = __expf(e0);
        e1 = (e1 > 0.f) ? e1 : 0.2f * e1;  float w1 = __expf(e1);
        e2 = (e2 > 0.f) ? e2 : 0.2f * e2;  float w2 = __expf(e2);
        e3 = (e3 > 0.f) ? e3 : 0.2f * e3;  float w3 = __expf(e3);
        den += (w0 + w1) + (w2 + w3);
        acc0 += w0 * (float)a0[0] + w1 * (float)a1[0] + w2 * (float)a2[0] + w3 * (float)a3[0];
        acc1 += w0 * (float)a0[1] + w1 * (float)a1[1] + w2 * (float)a2[1] + w3 * (float)a3[1];
    }
    for (; p < pe; ++p) {
        int src = csr_src[p];
        float e = s_src[src] + sd;
        e = (e > 0.f) ? e : 0.2f * e;
        float wgt = __expf(e);
        den += wgt;
        half2v av = *((const half2v*)(h + (size_t)src * 128) + lane);
        acc0 += wgt * (float)av[0];
        acc1 += wgt * (float)av[1];
    }
    float inv = 1.f / den;                    // self-loop guarantees den > 0
    float2 bv = *((const float2*)bias + lane);
    float v0 = acc0 * inv + bv.x;
    float v1 = acc1 * inv + bv.y;
    v0 = (v0 > 0.f) ? v0 : 0.2f * v0;
    v1 = (v1 > 0.f) ? v1 : 0.2f * v1;
    _Float16 h0 = (_Float16)v0, h1 = (_Float16)v1;
    size_t base = (size_t)node * 128 + 2 * lane;
    *(half2v*)(xh + base) = (half2v){h0, h1};
    *(half2v*)(xl + base) = (half2v){(_Float16)(v0 - (float)h0), (_Float16)(v1 - (float)h1)};
}

// ---------------- shared GEMM machinery ----------
// R18+R19: 8 waves (4M x 2N, acc[2][4]) + LDS-restaged C epilogue.
// R21 (BK=64): barrier pairs halved -> head 95->92. All GEMMs at ~34%
// MfmaUtil = the "2-phase" plateau; residual = exposed stage-drain.
// R22: BK=32 DOUBLE-BUFFERED at the SAME 64KiB (iso-LDS retry of R3's dbuf,
// which was confounded by a 32->64KB occupancy loss). STAGE(t+1) issued
// before compute(t) -> vmcnt(0) at step end covered by ~600cy of compute.
// Raw s_barrier safe: compiler's lgkmcnt waits before MFMAs guarantee each
// wave's ds_reads complete before its barrier; vmcnt(0)+barrier guards swap.
__device__ __forceinline__ void gload_lds16(const void* g, void* l) {
    __builtin_amdgcn_global_load_lds(
        (const __attribute__((address_space(1))) void*)g,
        (__attribute__((address_space(3))) void*)l, 16, 0, 0);
}

// per-block phase stagger: hash(bid) -> 0..7 sleeps of ~512cy. ~free, tiny win.
__device__ __forceinline__ void phase_stagger(int bid) {
    int ph = (int)(((unsigned)bid * 2654435761u) >> 29);
    for (int i = 0; i < ph; ++i) __builtin_amdgcn_s_sleep(8);
}

// ---------------- generic split-f16 MFMA GEMM (8-wave, dbuf BK=32; gemm0/gemm1) ----
__global__ __launch_bounds__(512) void k_mgemm(
    const _Float16* __restrict__ Ahi, const _Float16* __restrict__ Alo,
    const _Float16* __restrict__ Bhi, const _Float16* __restrict__ Blo,
    const float* __restrict__ bias, float* __restrict__ Cf,
    _Float16* __restrict__ Chi, _Float16* __restrict__ Clo,
    int M, int N, int K, int relu, int split, int nx, int ntiles)
{
    __shared__ _Float16 sm[2][4][128][32];   // 64 KiB: dbuf x {Ahi,Alo,Bhi,Blo}

    int bid = blockIdx.x;
    int per = (ntiles + 7) >> 3;
    int g = (bid & 7) * per + (bid >> 3);
    if (g >= ntiles) return;
    int col0 = (g % nx) * 128;
    int row0 = (g / nx) * 128;

    phase_stagger(bid);

    int t = threadIdx.x;
    int w = t >> 6, lane = t & 63;
    int wm = (w & 3) * 32, wn = (w >> 2) * 64;   // 8 waves = 4M x 2N, wave tile 32x64
    int fr = lane & 15;
    int fq = lane >> 4, fq8 = fq * 8;

    int srow = t >> 2;                // 0..127
    int scol = (t & 3) << 3;          // halfs
    int lrow = w << 4;                // wave-uniform LDS base row

    int ga = row0 + srow; if (ga > M - 1) ga = M - 1;  // M-tail: dup reads, guarded at store
    int gb = col0 + srow;                               // N % 128 == 0 -> in range

    f32x4 acc[2][4];
    #pragma unroll
    for (int i = 0; i < 2; i++)
        #pragma unroll
        for (int j = 0; j < 4; j++) acc[i][j] = (f32x4){0.f, 0.f, 0.f, 0.f};

    auto STAGE = [&](int buf, int k0) {
        int kc = k0 + scol;
        gload_lds16(Ahi + (size_t)ga * K + kc, &sm[buf][0][lrow][0]);
        gload_lds16(Alo + (size_t)ga * K + kc, &sm[buf][1][lrow][0]);
        gload_lds16(Bhi + (size_t)gb * K + kc, &sm[buf][2][lrow][0]);
        gload_lds16(Blo + (size_t)gb * K + kc, &sm[buf][3][lrow][0]);
    };

    // prologue: stage step 0, drain, sync
    STAGE(0, 0);
    asm volatile("s_waitcnt vmcnt(0)" ::: "memory");
    __builtin_amdgcn_s_barrier();
    asm volatile("" ::: "memory");

    int NT = K >> 5;
    for (int tt = 0; tt < NT; ++tt) {
        int cur = tt & 1;
        if (tt + 1 < NT) STAGE(cur ^ 1, (tt + 1) << 5);   // issue next-step loads FIRST
        asm volatile("" ::: "memory");

        half8 bh[4], bl[4];
        #pragma unroll
        for (int ni = 0; ni < 4; ++ni) {
            bh[ni] = *(half8*)&sm[cur][2][wn + ni * 16 + fr][fq8];
            bl[ni] = *(half8*)&sm[cur][3][wn + ni * 16 + fr][fq8];
        }
        #pragma unroll
        for (int mi = 0; mi < 2; ++mi) {
            half8 ah = *(half8*)&sm[cur][0][wm + mi * 16 + fr][fq8];
            half8 al = *(half8*)&sm[cur][1][wm + mi * 16 + fr][fq8];
            #pragma unroll
            for (int ni = 0; ni < 4; ++ni) {
                acc[mi][ni] = __builtin_amdgcn_mfma_f32_16x16x32_f16(ah, bh[ni], acc[mi][ni], 0, 0, 0);
                acc[mi][ni] = __builtin_amdgcn_mfma_f32_16x16x32_f16(ah, bl[ni], acc[mi][ni], 0, 0, 0);
                acc[mi][ni] = __builtin_amdgcn_mfma_f32_16x16x32_f16(al, bh[ni], acc[mi][ni], 0, 0, 0);
            }
        }

        // step boundary: own next-step loads done (covered by compute above);
        // barrier publishes all waves' LDS writes + guards buffer reuse.
        asm volatile("s_waitcnt vmcnt(0)" ::: "memory");
        __builtin_amdgcn_s_barrier();
        asm volatile("" ::: "memory");
    }

    float bv[4];
    #pragma unroll
    for (int ni = 0; ni < 4; ++ni)
        bv[ni] = bias ? bias[col0 + wn + ni * 16 + fr] : 0.f;

    if (split) {
        // R19 epilogue: restage C via LDS -> 16B coalesced stores (pass 0: hi, 1: lo)
        _Float16* sc = &sm[0][0][0][0];   // first 32 KiB overlay [128][128]
        #pragma unroll
        for (int pass = 0; pass < 2; ++pass) {
            __syncthreads();
            #pragma unroll
            for (int mi = 0; mi < 2; ++mi) {
                #pragma unroll
                for (int ni = 0; ni < 4; ++ni) {
                    #pragma unroll
                    for (int r = 0; r < 4; ++r) {
                        int row = wm + mi * 16 + fq * 4 + r;
                        int col = wn + ni * 16 + fr;
                        float v = acc[mi][ni][r] + bv[ni];
                        if (relu) v = (v > 0.f) ? v : 0.f;
                        _Float16 hh = (_Float16)v;
                        sc[row * 128 + col] = pass ? (_Float16)(v - (float)hh) : hh;
                    }
                }
            }
            __syncthreads();
            _Float16* dst = pass ? Clo : Chi;
            #pragma unroll
            for (int pp = 0; pp < 4; ++pp) {
                int idx = t + pp * 512;
                int row = idx >> 4, seg = idx & 15;
                int gr = row0 + row;
                if (gr < M)
                    *(half8*)(dst + (size_t)gr * N + col0 + seg * 8) =
                        *(half8*)&sc[row * 128 + seg * 8];
            }
        }
    } else {
        #pragma unroll
        for (int ni = 0; ni < 4; ++ni) {
            #pragma unroll
            for (int mi = 0; mi < 2; ++mi) {
                #pragma unroll
                for (int r = 0; r < 4; ++r) {
                    int gr = row0 + wm + mi * 16 + fq * 4 + r;
                    if (gr >= M) continue;
                    float v = acc[mi][ni][r] + bv[ni];
                    if (relu) v = (v > 0.f) ? v : 0.f;
                    Cf[(size_t)gr * N + col0 + wn + ni * 16 + fr] = v;
                }
            }
        }
    }
}

// ---------------- GAT GEMM fused with attention scalars (N=K=128, 8-wave BK=64) ----
// Control: kept on the R21 single-buffer BK=64 path (only 2 K-steps).
__global__ __launch_bounds__(512) void k_mgemm_gat(
    const _Float16* __restrict__ Ahi, const _Float16* __restrict__ Alo,
    const _Float16* __restrict__ Bhi, const _Float16* __restrict__ Blo,
    const float* __restrict__ a_src, const float* __restrict__ a_dst,
    _Float16* __restrict__ hbuf, float* __restrict__ s_src, float* __restrict__ s_dst,
    int M, int ntiles)
{
    __shared__ _Float16 sm[4][2][128][32];   // 64 KiB; reused as hbuf C tile
    __shared__ float sps[2][128], spd[2][128];

    const int K = 128;
    int bid = blockIdx.x;
    int per = (ntiles + 7) >> 3;
    int g = (bid & 7) * per + (bid >> 3);
    if (g >= ntiles) return;
    int row0 = g * 128;                    // nx == 1 (N = 128)

    int t = threadIdx.x;
    int w = t >> 6, lane = t & 63;
    int wm = (w & 3) * 32, wn = (w >> 2) * 64;   // 8 waves = 4M x 2N
    int fr = lane & 15;
    int fq = lane >> 4, fq8 = fq * 8;
    int wnIdx = w >> 2;

    int srow = t >> 2;
    int scol = (t & 3) << 3;
    int lrow = w << 4;

    f32x4 acc[2][4];
    #pragma unroll
    for (int i = 0; i < 2; i++)
        #pragma unroll
        for (int j = 0; j < 4; j++) acc[i][j] = (f32x4){0.f, 0.f, 0.f, 0.f};

    for (int k0 = 0; k0 < K; k0 += 64) {
        if (k0) __syncthreads();
        {
            int ga = row0 + srow; if (ga > M - 1) ga = M - 1;
            int gb = srow;                                    // col0 = 0, N = 128
            #pragma unroll
            for (int kk = 0; kk < 2; ++kk) {
                int kc = k0 + kk * 32 + scol;
                gload_lds16(Ahi + (size_t)ga * K + kc, &sm[0][kk][lrow][0]);
                gload_lds16(Alo + (size_t)ga * K + kc, &sm[1][kk][lrow][0]);
                gload_lds16(Bhi + (size_t)gb * K + kc, &sm[2][kk][lrow][0]);
                gload_lds16(Blo + (size_t)gb * K + kc, &sm[3][kk][lrow][0]);
            }
        }
        __syncthreads();

        #pragma unroll
        for (int kk = 0; kk < 2; ++kk) {
            half8 bh[4], bl[4];
            #pragma unroll
            for (int ni = 0; ni < 4; ++ni) {
                bh[ni] = *(half8*)&sm[2][kk][wn + ni * 16 + fr][fq8];
                bl[ni] = *(half8*)&sm[3][kk][wn + ni * 16 + fr][fq8];
            }
            #pragma unroll
            for (int mi = 0; mi < 2; ++mi) {
                half8 ah = *(half8*)&sm[0][kk][wm + mi * 16 + fr][fq8];
                half8 al = *(half8*)&sm[1][kk][wm + mi * 16 + fr][fq8];
                #pragma unroll
                for (int ni = 0; ni < 4; ++ni) {
                    acc[mi][ni] = __builtin_amdgcn_mfma_f32_16x16x32_f16(ah, bh[ni], acc[mi][ni], 0, 0, 0);
                    acc[mi][ni] = __builtin_amdgcn_mfma_f32_16x16x32_f16(ah, bl[ni], acc[mi][ni], 0, 0, 0);
                    acc[mi][ni] = __builtin_amdgcn_mfma_f32_16x16x32_f16(al, bh[ni], acc[mi][ni], 0, 0, 0);
                }
            }
        }
    }

    // epilogue: scalar dots + restage hbuf via LDS
    float asv[4], adv[4];
    #pragma unroll
    for (int ni = 0; ni < 4; ++ni) {
        int gc = wn + ni * 16 + fr;
        asv[ni] = a_src[gc];
        adv[ni] = a_dst[gc];
    }
    __syncthreads();   // all waves done reading sm (K-loop) before overwrite
    _Float16* sc = &sm[0][0][0][0];   // [128][128]
    #pragma unroll
    for (int mi = 0; mi < 2; ++mi) {
        #pragma unroll
        for (int r = 0; r < 4; ++r) {
            int row = wm + mi * 16 + fq * 4 + r;
            float vps = 0.f, vpd = 0.f;
            #pragma unroll
            for (int ni = 0; ni < 4; ++ni) {
                float v = acc[mi][ni][r];
                vps += v * asv[ni];
                vpd += v * adv[ni];
                sc[row * 128 + wn + ni * 16 + fr] = (_Float16)v;
            }
            #pragma unroll
            for (int off = 1; off < 16; off <<= 1) {
                vps += __shfl_xor(vps, off);
                vpd += __shfl_xor(vpd, off);
            }
            if (fr == 0) { sps[wnIdx][row] = vps; spd[wnIdx][row] = vpd; }
        }
    }
    __syncthreads();
    if (t < 128) {
        int gr = row0 + t;
        if (gr < M) {
            s_src[gr] = sps[0][t] + sps[1][t];
            s_dst[gr] = spd[0][t] + spd[1][t];
        }
    }
    #pragma unroll
    for (int pp = 0; pp < 4; ++pp) {
        int idx = t + pp * 512;
        int row = idx >> 4, seg = idx & 15;
        int gr = row0 + row;
        if (gr < M)
            *(half8*)(hbuf + (size_t)gr * 128 + seg * 8) = *(half8*)&sc[row * 128 + seg * 8];
    }
}

// ---------------- gemm2 fused with MLP head (N=512, 8-wave dbuf BK=32, partials) ---
__global__ __launch_bounds__(512) void k_mgemm_head(
    const _Float16* __restrict__ Ahi, const _Float16* __restrict__ Alo,
    const _Float16* __restrict__ Bhi, const _Float16* __restrict__ Blo,
    const float* __restrict__ bias, const float* __restrict__ Wo,
    float* __restrict__ partial,
    int M, int K, int nx, int ntiles)
{
    __shared__ _Float16 sm[2][4][128][32];   // 64 KiB dbuf
    __shared__ float4 sacc[2][128];          // 4 KiB: per-wn-half row partials

    int bid = blockIdx.x;
    int per = (ntiles + 7) >> 3;
    int g = (bid & 7) * per + (bid >> 3);
    if (g >= ntiles) return;
    int ct = g % nx;
    int col0 = ct * 128;
    int row0 = (g / nx) * 128;

    phase_stagger(bid);

    int t = threadIdx.x;
    int w = t >> 6, lane = t & 63;
    int wm = (w & 3) * 32, wn = (w >> 2) * 64;   // 8 waves = 4M x 2N
    int fr = lane & 15;
    int fq = lane >> 4, fq8 = fq * 8;

    int srow = t >> 2;
    int scol = (t & 3) << 3;
    int lrow = w << 4;

    int ga = row0 + srow; if (ga > M - 1) ga = M - 1;
    int gb = col0 + srow;

    f32x4 acc[2][4];
    #pragma unroll
    for (int i = 0; i < 2; i++)
        #pragma unroll
        for (int j = 0; j < 4; j++) acc[i][j] = (f32x4){0.f, 0.f, 0.f, 0.f};

    auto STAGE = [&](int buf, int k0) {
        int kc = k0 + scol;
        gload_lds16(Ahi + (size_t)ga * K + kc, &sm[buf][0][lrow][0]);
        gload_lds16(Alo + (size_t)ga * K + kc, &sm[buf][1][lrow][0]);
        gload_lds16(Bhi + (size_t)gb * K + kc, &sm[buf][2][lrow][0]);
        gload_lds16(Blo + (size_t)gb * K + kc, &sm[buf][3][lrow][0]);
    };

    STAGE(0, 0);
    asm volatile("s_waitcnt vmcnt(0)" ::: "memory");
    __builtin_amdgcn_s_barrier();
    asm volatile("" ::: "memory");

    int NT = K >> 5;
    for (int tt = 0; tt < NT; ++tt) {
        int cur = tt & 1;
        if (tt + 1 < NT) STAGE(cur ^ 1, (tt + 1) << 5);
        asm volatile("" ::: "memory");

        half8 bh[4], bl[4];
        #pragma unroll
        for (int ni = 0; ni < 4; ++ni) {
            bh[ni] = *(half8*)&sm[cur][2][wn + ni * 16 + fr][fq8];
            bl[ni] = *(half8*)&sm[cur][3][wn + ni * 16 + fr][fq8];
        }
        #pragma unroll
        for (int mi = 0; mi < 2; ++mi) {
            half8 ah = *(half8*)&sm[cur][0][wm + mi * 16 + fr][fq8];
            half8 al = *(half8*)&sm[cur][1][wm + mi * 16 + fr][fq8];
            #pragma unroll
            for (int ni = 0; ni < 4; ++ni) {
                acc[mi][ni] = __builtin_amdgcn_mfma_f32_16x16x32_f16(ah, bh[ni], acc[mi][ni], 0, 0, 0);
                acc[mi][ni] = __builtin_amdgcn_mfma_f32_16x16x32_f16(ah, bl[ni], acc[mi][ni], 0, 0, 0);
                acc[mi][ni] = __builtin_amdgcn_mfma_f32_16x16x32_f16(al, bh[ni], acc[mi][ni], 0, 0, 0);
            }
        }

        asm volatile("s_waitcnt vmcnt(0)" ::: "memory");
        __builtin_amdgcn_s_barrier();
        asm volatile("" ::: "memory");
    }

    // epilogue: relu(acc+b2) contracted with Wo -> LDS combine -> partial write
    float bv[4];
    float4 wv[4];
    #pragma unroll
    for (int ni = 0; ni < 4; ++ni) {
        int gc = col0 + wn + ni * 16 + fr;
        bv[ni] = bias[gc];
        wv[ni] = *(const float4*)(Wo + (size_t)gc * 4);
    }
    #pragma unroll
    for (int mi = 0; mi < 2; ++mi) {
        #pragma unroll
        for (int r = 0; r < 4; ++r) {
            int row = wm + mi * 16 + fq * 4 + r;
            float o0 = 0.f, o1 = 0.f, o2 = 0.f, o3 = 0.f;
            #pragma unroll
            for (int ni = 0; ni < 4; ++ni) {
                float v = acc[mi][ni][r] + bv[ni];
                v = (v > 0.f) ? v : 0.f;
                o0 += v * wv[ni].x; o1 += v * wv[ni].y;
                o2 += v * wv[ni].z; o3 += v * wv[ni].w;
            }
            #pragma unroll
            for (int off = 1; off < 16; off <<= 1) {
                o0 += __shfl_xor(o0, off); o1 += __shfl_xor(o1, off);
                o2 += __shfl_xor(o2, off); o3 += __shfl_xor(o3, off);
            }
            if (fr == 0) sacc[w >> 2][row] = (float4){o0, o1, o2, o3};
        }
    }
    __syncthreads();
    if (t < 128) {
        int gr = row0 + t;
        if (gr < M) {
            float4 s0 = sacc[0][t], s1 = sacc[1][t];
            float4 o = (float4){s0.x + s1.x, s0.y + s1.y, s0.z + s1.z, s0.w + s1.w};
            *(float4*)(partial + ((size_t)ct * M + gr) * 4) = o;
        }
    }
}

// ---------------- reduce 4 col-tile partials -> out (adds bo) ----------------
__global__ __launch_bounds__(256) void k_headred(const float* __restrict__ partial,
                                                 const float* __restrict__ bo,
                                                 float* __restrict__ out, int M) {
    int r = blockIdx.x * 256 + threadIdx.x;
    if (r >= M) return;
    float4 a = *(const float4*)(partial + ((size_t)0 * M + r) * 4);
    float4 b = *(const float4*)(partial + ((size_t)1 * M + r) * 4);
    float4 c = *(const float4*)(partial + ((size_t)2 * M + r) * 4);
    float4 d = *(const float4*)(partial + ((size_t)3 * M + r) * 4);
    float4 o;
    o.x = a.x + b.x + c.x + d.x + bo[0];
    o.y = a.y + b.y + c.y + d.y + bo[1];
    o.z = a.z + b.z + c.z + d.z + bo[2];
    o.w = a.w + b.w + c.w + d.w + bo[3];
    *(float4*)(out + (size_t)r * 4) = o;
}

extern "C" void kernel_launch(void* const* d_in, const int* in_sizes, int n_in,
                              void* d_out, int out_size, void* d_ws, size_t ws_size,
                              hipStream_t stream) {
    const float* x    = (const float*)d_in[0];
    const int*   eidx = (const int*)d_in[1];
    const float* cW   = (const float*)d_in[2];
    const float* caS  = (const float*)d_in[3];
    const float* caD  = (const float*)d_in[4];
    const float* cB   = (const float*)d_in[5];
    const float* W0   = (const float*)d_in[6];
    const float* b0   = (const float*)d_in[7];
    const float* W1   = (const float*)d_in[8];
    const float* b1   = (const float*)d_in[9];
    const float* W2   = (const float*)d_in[10];
    const float* b2   = (const float*)d_in[11];
    const float* Wo   = (const float*)d_in[12];
    const float* bo   = (const float*)d_in[13];
    (void)in_sizes; (void)n_in; (void)out_size;

    const int* esrc = eidx;
    const int* edst = eidx + NE;
    float* out = (float*)d_out;

    // ---- workspace bump allocator (256B aligned) ----
    char* w = (char*)d_ws;
    auto alloc = [&](size_t bytes) -> char* {
        char* p = w;
        w += (bytes + 255) & ~(size_t)255;
        return p;
    };
    _Float16* x0h  = (_Float16*)alloc((size_t)NN * 128 * 2);
    _Float16* x0l  = (_Float16*)alloc((size_t)NN * 128 * 2);
    _Float16* xh   = (_Float16*)alloc((size_t)NN * 128 * 2);
    _Float16* xl   = (_Float16*)alloc((size_t)NN * 128 * 2);
    _Float16* hbuf = (_Float16*)alloc((size_t)NN * 128 * 2);   // f16 (R17)
    float* ssrc    = (float*)alloc((size_t)NN * 4);
    float* sdst    = (float*)alloc((size_t)NN * 4);
    int*   counts  = (int*)  alloc((size_t)NN * 4);
    int*   offs    = (int*)  alloc((size_t)(NN + 1) * 4);
    int*   cursor  = (int*)  alloc((size_t)NN * 4);
    int*   csr     = (int*)  alloc((size_t)NET * 4);
    int*   part    = (int*)  alloc((size_t)SCAN_NB * 4);
    _Float16* cwh  = (_Float16*)alloc(3 * 128 * 128 * 2);
    _Float16* cwl  = (_Float16*)alloc(3 * 128 * 128 * 2);
    _Float16* w0h  = (_Float16*)alloc(512 * 128 * 2);
    _Float16* w0l  = (_Float16*)alloc(512 * 128 * 2);
    _Float16* w1h  = (_Float16*)alloc(512 * 512 * 2);
    _Float16* w1l  = (_Float16*)alloc(512 * 512 * 2);
    _Float16* w2h  = (_Float16*)alloc(512 * 512 * 2);
    _Float16* w2l  = (_Float16*)alloc(512 * 512 * 2);
    float* hpart   = (float*)alloc((size_t)4 * NN * 4 * 4);   // head partials [4][NN][4]

    size_t used = (size_t)(w - (char*)d_ws);
    size_t rem = (ws_size > used) ? (ws_size - used) : 0;
    int chunk = (int)(rem / (4 * 512 * sizeof(_Float16)));
    if (chunk > NN) chunk = NN;
    if (chunk > 128) chunk &= ~127;
    if (chunk < 1) chunk = 1;
    _Float16* Y0h = (_Float16*)alloc((size_t)chunk * 512 * 2);
    _Float16* Y0l = (_Float16*)alloc((size_t)chunk * 512 * 2);
    _Float16* Y1h = (_Float16*)alloc((size_t)chunk * 512 * 2);
    _Float16* Y1l = (_Float16*)alloc((size_t)chunk * 512 * 2);

    auto gemm = [&](const _Float16* Ah, const _Float16* Al,
                    const _Float16* Bh, const _Float16* Bl,
                    const float* bias, float* Cf, _Float16* Ch, _Float16* Cl,
                    int M, int N, int K, int relu, int split) {
        int nx = N / 128;
        int ntiles = nx * ((M + 127) / 128);
        int nb = ((ntiles + 7) / 8) * 8;
        k_mgemm<<<nb, 512, 0, stream>>>(Ah, Al, Bh, Bl, bias, Cf, Ch, Cl,
                                        M, N, K, relu, split, nx, ntiles);
    };

    // ---- prep: split x, transpose+split weights ----
    k_split<<<2048, 256, 0, stream>>>(x, x0h, x0l, NN * 128);
    for (int L = 0; L < 3; ++L)
        k_prepw<<<dim3(128 / 32, 128 / 32), 256, 0, stream>>>(
            cW + (size_t)L * 128 * 128, cwh + (size_t)L * 128 * 128, cwl + (size_t)L * 128 * 128, 128, 128);
    k_prepw<<<dim3(512 / 32, 128 / 32), 256, 0, stream>>>(W0, w0h, w0l, 128, 512);
    k_prepw<<<dim3(512 / 32, 512 / 32), 256, 0, stream>>>(W1, w1h, w1l, 512, 512);
    k_prepw<<<dim3(512 / 32, 512 / 32), 256, 0, stream>>>(W2, w2h, w2l, 512, 512);

    // ---- build CSR once ----
    hipMemsetAsync(counts, 0, (size_t)NN * 4, stream);
    int eblocks = (NET + 255) / 256;
    k_count <<<eblocks, 256, 0, stream>>>(edst, counts);
    k_scan1 <<<SCAN_NB, 256, 0, stream>>>(counts, part);
    k_scan2 <<<1, 256, 0, stream>>>(part, offs);
    k_scan3 <<<SCAN_NB, 256, 0, stream>>>(counts, part, offs, cursor);
    k_scatter<<<eblocks, 256, 0, stream>>>(esrc, edst, cursor, csr);

    // ---- 3 GAT layers (GEMM fused with attention scalars) ----
    int gat_tiles = (NN + 127) / 128;
    int gat_nb = ((gat_tiles + 7) / 8) * 8;
    for (int L = 0; L < 3; ++L) {
        const _Float16* Ah = (L == 0) ? x0h : xh;
        const _Float16* Al = (L == 0) ? x0l : xl;
        k_mgemm_gat<<<gat_nb, 512, 0, stream>>>(
            Ah, Al, cwh + (size_t)L * 128 * 128, cwl + (size_t)L * 128 * 128,
            caS + L * 128, caD + L * 128, hbuf, ssrc, sdst, NN, gat_tiles);
        k_aggregate<<<NN / 4, 256, 0, stream>>>(hbuf, ssrc, sdst, offs, csr, cB + L * 128, xh, xl);
    }

    // ---- MLP head (chunked over nodes; gemm2 fused with output head) ----
    for (int m0 = 0; m0 < NN; m0 += chunk) {
        int cm = imin(chunk, NN - m0);
        gemm(xh + (size_t)m0 * 128, xl + (size_t)m0 * 128, w0h, w0l, b0,
             nullptr, Y0h, Y0l, cm, 512, 128, 1, 1);
        gemm(Y0h, Y0l, w1h, w1l, b1, nullptr, Y1h, Y1l, cm, 512, 512, 1, 1);
        int nx = 4;
        int ntiles = nx * ((cm + 127) / 128);
        int nb = ((ntiles + 7) / 8) * 8;
        k_mgemm_head<<<nb, 512, 0, stream>>>(Y1h, Y1l, w2h, w2l, b2, Wo,
                                             hpart, cm, 512, nx, ntiles);
        k_headred<<<(cm + 255) / 256, 256, 0, stream>>>(hpart, bo, out + (size_t)m0 * 4, cm);
    }
}

// Round 14
// 624.513 us; speedup vs baseline: 1.0273x; 1.0273x over previous
//
#include <hip/hip_runtime.h>
#include <hip/hip_bf16.h>

#define NN 50000
#define NE 800000
#define NET (NE + NN)
#define SCAN_NB ((NN + 255) / 256)   // 196

static inline int imin(int a, int b) { return a < b ? a : b; }

typedef _Float16 half8 __attribute__((ext_vector_type(8)));
typedef _Float16 half2v __attribute__((ext_vector_type(2)));
typedef float f32x4 __attribute__((ext_vector_type(4)));

// ---------------- CSR build (graph constant across layers) ----------------
__global__ void k_count(const int* __restrict__ edst, int* __restrict__ counts) {
    int e = blockIdx.x * blockDim.x + threadIdx.x;
    if (e >= NET) return;
    int d = (e < NE) ? edst[e] : (e - NE);   // self loops appended
    atomicAdd(&counts[d], 1);
}

__global__ __launch_bounds__(256) void k_scan1(const int* __restrict__ counts,
                                               int* __restrict__ part) {
    __shared__ int s[256];
    int t = threadIdx.x, i = blockIdx.x * 256 + t;
    s[t] = (i < NN) ? counts[i] : 0;
    __syncthreads();
    for (int off = 128; off > 0; off >>= 1) {
        if (t < off) s[t] += s[t + off];
        __syncthreads();
    }
    if (t == 0) part[blockIdx.x] = s[0];
}

__global__ __launch_bounds__(256) void k_scan2(int* __restrict__ part, int* __restrict__ offs) {
    __shared__ int s[256];
    int t = threadIdx.x;
    int v = (t < SCAN_NB) ? part[t] : 0;
    s[t] = v;
    __syncthreads();
    for (int off = 1; off < 256; off <<= 1) {
        int a = (t >= off) ? s[t - off] : 0;
        __syncthreads();
        s[t] += a;
        __syncthreads();
    }
    if (t < SCAN_NB) part[t] = s[t] - v;     // exclusive block offsets
    if (t == 255) offs[NN] = s[255];         // total (= NET)
}

__global__ __launch_bounds__(256) void k_scan3(const int* __restrict__ counts,
                                               const int* __restrict__ part,
                                               int* __restrict__ offs, int* __restrict__ cursor) {
    __shared__ int s[256];
    int t = threadIdx.x, i = blockIdx.x * 256 + t;
    int v = (i < NN) ? counts[i] : 0;
    s[t] = v;
    __syncthreads();
    for (int off = 1; off < 256; off <<= 1) {
        int a = (t >= off) ? s[t - off] : 0;
        __syncthreads();
        s[t] += a;
        __syncthreads();
    }
    if (i < NN) {
        int e = part[blockIdx.x] + s[t] - v;
        offs[i] = e;
        cursor[i] = e;
    }
}

__global__ void k_scatter(const int* __restrict__ esrc, const int* __restrict__ edst,
                          int* __restrict__ cursor, int* __restrict__ csr_src) {
    int e = blockIdx.x * blockDim.x + threadIdx.x;
    if (e >= NET) return;
    int s, d;
    if (e < NE) { s = esrc[e]; d = edst[e]; } else { s = e - NE; d = s; }
    int pos = atomicAdd(&cursor[d], 1);
    csr_src[pos] = s;
}

// ---------------- split fp32 -> f16 hi/lo pair ----------------
__global__ void k_split(const float* __restrict__ in, _Float16* __restrict__ hi,
                        _Float16* __restrict__ lo, int n) {
    int i = blockIdx.x * blockDim.x + threadIdx.x;
    int st = gridDim.x * blockDim.x;
    for (; i < n; i += st) {
        float v = in[i];
        _Float16 h = (_Float16)v;
        hi[i] = h;
        lo[i] = (_Float16)(v - (float)h);
    }
}

// ---------------- transpose + split weights: W[K][N] -> T[N][K] hi/lo (LDS-tiled) ----
__global__ __launch_bounds__(256) void k_prepw(const float* __restrict__ W,
                                               _Float16* __restrict__ Th,
                                               _Float16* __restrict__ Tl, int K, int N) {
    __shared__ float tile[32][33];
    int tx = threadIdx.x & 31, ty = threadIdx.x >> 5;
    int n0 = blockIdx.x * 32, k0 = blockIdx.y * 32;
    #pragma unroll
    for (int r = ty; r < 32; r += 8)
        tile[r][tx] = W[(size_t)(k0 + r) * N + n0 + tx];   // coalesced read
    __syncthreads();
    #pragma unroll
    for (int r = ty; r < 32; r += 8) {
        int n = n0 + r, k = k0 + tx;
        float v = tile[tx][r];
        _Float16 h = (_Float16)v;
        Th[(size_t)n * K + k] = h;                          // coalesced 64B segments
        Tl[(size_t)n * K + k] = (_Float16)(v - (float)h);
    }
}

// ---------------- fused segment-softmax + aggregate + bias + leaky ----------------
// R17: hbuf f16. R23: 8-edge unroll + split accumulators — the gather loop is
// latency-bound (chain of index->score->row loads, avg degree 17); 8-deep
// doubles outstanding loads per wave and halves dependent latency rounds.
// fp32 reassociation only (regrouped sums) — absmax unaffected at 1e-4 scale.
__global__ void k_aggregate(const _Float16* __restrict__ h, const float* __restrict__ s_src,
                            const float* __restrict__ s_dst, const int* __restrict__ offs,
                            const int* __restrict__ csr_src, const float* __restrict__ bias,
                            _Float16* __restrict__ xh, _Float16* __restrict__ xl) {
    int node = blockIdx.x * 4 + (threadIdx.x >> 6);
    int lane = threadIdx.x & 63;
    if (node >= NN) return;
    int p = offs[node], pe = offs[node + 1];
    float sd = s_dst[node];
    float den0 = 0.f, den1 = 0.f;
    float a00 = 0.f, a01 = 0.f, a10 = 0.f, a11 = 0.f;
    for (; p + 8 <= pe; p += 8) {
        int s0 = csr_src[p + 0], s1 = csr_src[p + 1];
        int s2 = csr_src[p + 2], s3 = csr_src[p + 3];
        int s4 = csr_src[p + 4], s5 = csr_src[p + 5];
        int s6 = csr_src[p + 6], s7 = csr_src[p + 7];
        float e0 = s_src[s0] + sd, e1 = s_src[s1] + sd;
        float e2 = s_src[s2] + sd, e3 = s_src[s3] + sd;
        float e4 = s_src[s4] + sd, e5 = s_src[s5] + sd;
        float e6 = s_src[s6] + sd, e7 = s_src[s7] + sd;
        half2v a0 = *((const half2v*)(h + (size_t)s0 * 128) + lane);
        half2v a1 = *((const half2v*)(h + (size_t)s1 * 128) + lane);
        half2v a2 = *((const half2v*)(h + (size_t)s2 * 128) + lane);
        half2v a3 = *((const half2v*)(h + (size_t)s3 * 128) + lane);
        half2v a4 = *((const half2v*)(h + (size_t)s4 * 128) + lane);
        half2v a5 = *((const half2v*)(h + (size_t)s5 * 128) + lane);
        half2v a6 = *((const half2v*)(h + (size_t)s6 * 128) + lane);
        half2v a7 = *((const half2v*)(h + (size_t)s7 * 128) + lane);
        e0 = (e0 > 0.f) ? e0 : 0.2f * e0;  float w0 = __expf(e0);
        e1 = (e1 > 0.f) ? e1 : 0.2f * e1;  float w1 = __expf(e1);
        e2 = (e2 > 0.f) ? e2 : 0.2f * e2;  float w2 = __expf(e2);
        e3 = (e3 > 0.f) ? e3 : 0.2f * e3;  float w3 = __expf(e3);
        e4 = (e4 > 0.f) ? e4 : 0.2f * e4;  float w4 = __expf(e4);
        e5 = (e5 > 0.f) ? e5 : 0.2f * e5;  float w5 = __expf(e5);
        e6 = (e6 > 0.f) ? e6 : 0.2f * e6;  float w6 = __expf(e6);
        e7 = (e7 > 0.f) ? e7 : 0.2f * e7;  float w7 = __expf(e7);
        den0 += (w0 + w1) + (w2 + w3);
        den1 += (w4 + w5) + (w6 + w7);
        a00 += w0 * (float)a0[0] + w1 * (float)a1[0] + w2 * (float)a2[0] + w3 * (float)a3[0];
        a01 += w0 * (float)a0[1] + w1 * (float)a1[1] + w2 * (float)a2[1] + w3 * (float)a3[1];
        a10 += w4 * (float)a4[0] + w5 * (float)a5[0] + w6 * (float)a6[0] + w7 * (float)a7[0];
        a11 += w4 * (float)a4[1] + w5 * (float)a5[1] + w6 * (float)a6[1] + w7 * (float)a7[1];
    }
    for (; p + 4 <= pe; p += 4) {
        int s0 = csr_src[p + 0], s1 = csr_src[p + 1];
        int s2 = csr_src[p + 2], s3 = csr_src[p + 3];
        float e0 = s_src[s0] + sd, e1 = s_src[s1] + sd;
        float e2 = s_src[s2] + sd, e3 = s_src[s3] + sd;
        half2v a0 = *((const half2v*)(h + (size_t)s0 * 128) + lane);
        half2v a1 = *((const half2v*)(h + (size_t)s1 * 128) + lane);
        half2v a2 = *((const half2v*)(h + (size_t)s2 * 128) + lane);
        half2v a3 = *((const half2v*)(h + (size_t)s3 * 128) + lane);
        e0 = (e0 > 0.f) ? e0 : 0.2f * e0;  float w0 = __expf(e0);
        e1 = (e1 > 0.f) ? e1 : 0.2f * e1;  float w1 = __expf(e1);
        e2 = (e2 > 0.f) ? e2 : 0.2f * e2;  float w2 = __expf(e2);
        e3 = (e3 > 0.f) ? e3 : 0.2f * e3;  float w3 = __expf(e3);
        den0 += (w0 + w1) + (w2 + w3);
        a00 += w0 * (float)a0[0] + w1 * (float)a1[0] + w2 * (float)a2[0] + w3 * (float)a3[0];
        a01 += w0 * (float)a0[1] + w1 * (float)a1[1] + w2 * (float)a2[1] + w3 * (float)a3[1];
    }
    for (; p < pe; ++p) {
        int src = csr_src[p];
        float e = s_src[src] + sd;
        e = (e > 0.f) ? e : 0.2f * e;
        float wgt = __expf(e);
        den0 += wgt;
        half2v av = *((const half2v*)(h + (size_t)src * 128) + lane);
        a00 += wgt * (float)av[0];
        a01 += wgt * (float)av[1];
    }
    float den = den0 + den1;
    float acc0 = a00 + a10, acc1 = a01 + a11;
    float inv = 1.f / den;                    // self-loop guarantees den > 0
    float2 bv = *((const float2*)bias + lane);
    float v0 = acc0 * inv + bv.x;
    float v1 = acc1 * inv + bv.y;
    v0 = (v0 > 0.f) ? v0 : 0.2f * v0;
    v1 = (v1 > 0.f) ? v1 : 0.2f * v1;
    _Float16 h0 = (_Float16)v0, h1 = (_Float16)v1;
    size_t base = (size_t)node * 128 + 2 * lane;
    *(half2v*)(xh + base) = (half2v){h0, h1};
    *(half2v*)(xl + base) = (half2v){(_Float16)(v0 - (float)h0), (_Float16)(v1 - (float)h1)};
}

// ---------------- shared GEMM machinery (R11 structure — measured best, 639µs) ----
// R18+R19: 8 waves (4M x 2N, acc[2][4]) + LDS-restaged C epilogue.
// R21: BK=64 as two BK=32 subtiles (barrier pairs halved). R22's iso-LDS
// dbuf retry was null-to-negative (642µs, head 92->95) — reproduces m99/m100:
// implicit wave-level overlap already captures pipelining at this shape.
// GEMM schedule space exhausted; R11 kernels restored verbatim.
__device__ __forceinline__ void gload_lds16(const void* g, void* l) {
    __builtin_amdgcn_global_load_lds(
        (const __attribute__((address_space(1))) void*)g,
        (__attribute__((address_space(3))) void*)l, 16, 0, 0);
}

// per-block phase stagger: hash(bid) -> 0..7 sleeps of ~512cy. ~free, tiny win.
__device__ __forceinline__ void phase_stagger(int bid) {
    int ph = (int)(((unsigned)bid * 2654435761u) >> 29);
    for (int i = 0; i < ph; ++i) __builtin_amdgcn_s_sleep(8);
}

// ---------------- generic split-f16 MFMA GEMM (8-wave, BK=64; gemm0/gemm1) ----
__global__ __launch_bounds__(512) void k_mgemm(
    const _Float16* __restrict__ Ahi, const _Float16* __restrict__ Alo,
    const _Float16* __restrict__ Bhi, const _Float16* __restrict__ Blo,
    const float* __restrict__ bias, float* __restrict__ Cf,
    _Float16* __restrict__ Chi, _Float16* __restrict__ Clo,
    int M, int N, int K, int relu, int split, int nx, int ntiles)
{
    __shared__ _Float16 sm[4][2][128][32];   // 64 KiB; reused as C tile (first 32 KiB)

    int bid = blockIdx.x;
    int per = (ntiles + 7) >> 3;
    int g = (bid & 7) * per + (bid >> 3);
    if (g >= ntiles) return;
    int col0 = (g % nx) * 128;
    int row0 = (g / nx) * 128;

    phase_stagger(bid);

    int t = threadIdx.x;
    int w = t >> 6, lane = t & 63;
    int wm = (w & 3) * 32, wn = (w >> 2) * 64;   // 8 waves = 4M x 2N, wave tile 32x64
    int fr = lane & 15;
    int fq = lane >> 4, fq8 = fq * 8;

    int srow = t >> 2;                // 0..127
    int scol = (t & 3) << 3;          // halfs
    int lrow = w << 4;                // wave-uniform LDS base row

    f32x4 acc[2][4];
    #pragma unroll
    for (int i = 0; i < 2; i++)
        #pragma unroll
        for (int j = 0; j < 4; j++) acc[i][j] = (f32x4){0.f, 0.f, 0.f, 0.f};

    for (int k0 = 0; k0 < K; k0 += 64) {
        if (k0) __syncthreads();
        {
            int ga = row0 + srow; if (ga > M - 1) ga = M - 1;  // M-tail: dup reads, guarded at store
            int gb = col0 + srow;                               // N % 128 == 0 -> in range
            #pragma unroll
            for (int kk = 0; kk < 2; ++kk) {
                int kc = k0 + kk * 32 + scol;
                gload_lds16(Ahi + (size_t)ga * K + kc, &sm[0][kk][lrow][0]);
                gload_lds16(Alo + (size_t)ga * K + kc, &sm[1][kk][lrow][0]);
                gload_lds16(Bhi + (size_t)gb * K + kc, &sm[2][kk][lrow][0]);
                gload_lds16(Blo + (size_t)gb * K + kc, &sm[3][kk][lrow][0]);
            }
        }
        __syncthreads();   // drains vmcnt -> gload_lds stores visible to all waves

        #pragma unroll
        for (int kk = 0; kk < 2; ++kk) {
            half8 bh[4], bl[4];
            #pragma unroll
            for (int ni = 0; ni < 4; ++ni) {
                bh[ni] = *(half8*)&sm[2][kk][wn + ni * 16 + fr][fq8];
                bl[ni] = *(half8*)&sm[3][kk][wn + ni * 16 + fr][fq8];
            }
            #pragma unroll
            for (int mi = 0; mi < 2; ++mi) {
                half8 ah = *(half8*)&sm[0][kk][wm + mi * 16 + fr][fq8];
                half8 al = *(half8*)&sm[1][kk][wm + mi * 16 + fr][fq8];
                #pragma unroll
                for (int ni = 0; ni < 4; ++ni) {
                    acc[mi][ni] = __builtin_amdgcn_mfma_f32_16x16x32_f16(ah, bh[ni], acc[mi][ni], 0, 0, 0);
                    acc[mi][ni] = __builtin_amdgcn_mfma_f32_16x16x32_f16(ah, bl[ni], acc[mi][ni], 0, 0, 0);
                    acc[mi][ni] = __builtin_amdgcn_mfma_f32_16x16x32_f16(al, bh[ni], acc[mi][ni], 0, 0, 0);
                }
            }
        }
    }

    float bv[4];
    #pragma unroll
    for (int ni = 0; ni < 4; ++ni)
        bv[ni] = bias ? bias[col0 + wn + ni * 16 + fr] : 0.f;

    if (split) {
        // R19 epilogue: restage C via LDS -> 16B coalesced stores (pass 0: hi, 1: lo)
        _Float16* sc = &sm[0][0][0][0];   // [128][128] overlay (32 KiB)
        #pragma unroll
        for (int pass = 0; pass < 2; ++pass) {
            __syncthreads();
            #pragma unroll
            for (int mi = 0; mi < 2; ++mi) {
                #pragma unroll
                for (int ni = 0; ni < 4; ++ni) {
                    #pragma unroll
                    for (int r = 0; r < 4; ++r) {
                        int row = wm + mi * 16 + fq * 4 + r;
                        int col = wn + ni * 16 + fr;
                        float v = acc[mi][ni][r] + bv[ni];
                        if (relu) v = (v > 0.f) ? v : 0.f;
                        _Float16 hh = (_Float16)v;
                        sc[row * 128 + col] = pass ? (_Float16)(v - (float)hh) : hh;
                    }
                }
            }
            __syncthreads();
            _Float16* dst = pass ? Clo : Chi;
            #pragma unroll
            for (int pp = 0; pp < 4; ++pp) {
                int idx = t + pp * 512;
                int row = idx >> 4, seg = idx & 15;
                int gr = row0 + row;
                if (gr < M)
                    *(half8*)(dst + (size_t)gr * N + col0 + seg * 8) =
                        *(half8*)&sc[row * 128 + seg * 8];
            }
        }
    } else {
        #pragma unroll
        for (int ni = 0; ni < 4; ++ni) {
            #pragma unroll
            for (int mi = 0; mi < 2; ++mi) {
                #pragma unroll
                for (int r = 0; r < 4; ++r) {
                    int gr = row0 + wm + mi * 16 + fq * 4 + r;
                    if (gr >= M) continue;
                    float v = acc[mi][ni][r] + bv[ni];
                    if (relu) v = (v > 0.f) ? v : 0.f;
                    Cf[(size_t)gr * N + col0 + wn + ni * 16 + fr] = v;
                }
            }
        }
    }
}

// ---------------- GAT GEMM fused with attention scalars (N=K=128, 8-wave BK=64) ----
__global__ __launch_bounds__(512) void k_mgemm_gat(
    const _Float16* __restrict__ Ahi, const _Float16* __restrict__ Alo,
    const _Float16* __restrict__ Bhi, const _Float16* __restrict__ Blo,
    const float* __restrict__ a_src, const float* __restrict__ a_dst,
    _Float16* __restrict__ hbuf, float* __restrict__ s_src, float* __restrict__ s_dst,
    int M, int ntiles)
{
    __shared__ _Float16 sm[4][2][128][32];   // 64 KiB; reused as hbuf C tile
    __shared__ float sps[2][128], spd[2][128];

    const int K = 128;
    int bid = blockIdx.x;
    int per = (ntiles + 7) >> 3;
    int g = (bid & 7) * per + (bid >> 3);
    if (g >= ntiles) return;
    int row0 = g * 128;                    // nx == 1 (N = 128)

    int t = threadIdx.x;
    int w = t >> 6, lane = t & 63;
    int wm = (w & 3) * 32, wn = (w >> 2) * 64;   // 8 waves = 4M x 2N
    int fr = lane & 15;
    int fq = lane >> 4, fq8 = fq * 8;
    int wnIdx = w >> 2;

    int srow = t >> 2;
    int scol = (t & 3) << 3;
    int lrow = w << 4;

    f32x4 acc[2][4];
    #pragma unroll
    for (int i = 0; i < 2; i++)
        #pragma unroll
        for (int j = 0; j < 4; j++) acc[i][j] = (f32x4){0.f, 0.f, 0.f, 0.f};

    for (int k0 = 0; k0 < K; k0 += 64) {
        if (k0) __syncthreads();
        {
            int ga = row0 + srow; if (ga > M - 1) ga = M - 1;
            int gb = srow;                                    // col0 = 0, N = 128
            #pragma unroll
            for (int kk = 0; kk < 2; ++kk) {
                int kc = k0 + kk * 32 + scol;
                gload_lds16(Ahi + (size_t)ga * K + kc, &sm[0][kk][lrow][0]);
                gload_lds16(Alo + (size_t)ga * K + kc, &sm[1][kk][lrow][0]);
                gload_lds16(Bhi + (size_t)gb * K + kc, &sm[2][kk][lrow][0]);
                gload_lds16(Blo + (size_t)gb * K + kc, &sm[3][kk][lrow][0]);
            }
        }
        __syncthreads();

        #pragma unroll
        for (int kk = 0; kk < 2; ++kk) {
            half8 bh[4], bl[4];
            #pragma unroll
            for (int ni = 0; ni < 4; ++ni) {
                bh[ni] = *(half8*)&sm[2][kk][wn + ni * 16 + fr][fq8];
                bl[ni] = *(half8*)&sm[3][kk][wn + ni * 16 + fr][fq8];
            }
            #pragma unroll
            for (int mi = 0; mi < 2; ++mi) {
                half8 ah = *(half8*)&sm[0][kk][wm + mi * 16 + fr][fq8];
                half8 al = *(half8*)&sm[1][kk][wm + mi * 16 + fr][fq8];
                #pragma unroll
                for (int ni = 0; ni < 4; ++ni) {
                    acc[mi][ni] = __builtin_amdgcn_mfma_f32_16x16x32_f16(ah, bh[ni], acc[mi][ni], 0, 0, 0);
                    acc[mi][ni] = __builtin_amdgcn_mfma_f32_16x16x32_f16(ah, bl[ni], acc[mi][ni], 0, 0, 0);
                    acc[mi][ni] = __builtin_amdgcn_mfma_f32_16x16x32_f16(al, bh[ni], acc[mi][ni], 0, 0, 0);
                }
            }
        }
    }

    // epilogue: scalar dots + restage hbuf via LDS
    float asv[4], adv[4];
    #pragma unroll
    for (int ni = 0; ni < 4; ++ni) {
        int gc = wn + ni * 16 + fr;
        asv[ni] = a_src[gc];
        adv[ni] = a_dst[gc];
    }
    __syncthreads();   // all waves done reading sm (K-loop) before overwrite
    _Float16* sc = &sm[0][0][0][0];   // [128][128]
    #pragma unroll
    for (int mi = 0; mi < 2; ++mi) {
        #pragma unroll
        for (int r = 0; r < 4; ++r) {
            int row = wm + mi * 16 + fq * 4 + r;
            float vps = 0.f, vpd = 0.f;
            #pragma unroll
            for (int ni = 0; ni < 4; ++ni) {
                float v = acc[mi][ni][r];
                vps += v * asv[ni];
                vpd += v * adv[ni];
                sc[row * 128 + wn + ni * 16 + fr] = (_Float16)v;
            }
            #pragma unroll
            for (int off = 1; off < 16; off <<= 1) {
                vps += __shfl_xor(vps, off);
                vpd += __shfl_xor(vpd, off);
            }
            if (fr == 0) { sps[wnIdx][row] = vps; spd[wnIdx][row] = vpd; }
        }
    }
    __syncthreads();
    if (t < 128) {
        int gr = row0 + t;
        if (gr < M) {
            s_src[gr] = sps[0][t] + sps[1][t];
            s_dst[gr] = spd[0][t] + spd[1][t];
        }
    }
    #pragma unroll
    for (int pp = 0; pp < 4; ++pp) {
        int idx = t + pp * 512;
        int row = idx >> 4, seg = idx & 15;
        int gr = row0 + row;
        if (gr < M)
            *(half8*)(hbuf + (size_t)gr * 128 + seg * 8) = *(half8*)&sc[row * 128 + seg * 8];
    }
}

// ---------------- gemm2 fused with MLP head (N=512, 8-wave BK=64, partials out) -----
__global__ __launch_bounds__(512) void k_mgemm_head(
    const _Float16* __restrict__ Ahi, const _Float16* __restrict__ Alo,
    const _Float16* __restrict__ Bhi, const _Float16* __restrict__ Blo,
    const float* __restrict__ bias, const float* __restrict__ Wo,
    float* __restrict__ partial,
    int M, int K, int nx, int ntiles)
{
    __shared__ _Float16 sm[4][2][128][32];   // 64 KiB
    __shared__ float4 sacc[2][128];          // 4 KiB: per-wn-half row partials

    int bid = blockIdx.x;
    int per = (ntiles + 7) >> 3;
    int g = (bid & 7) * per + (bid >> 3);
    if (g >= ntiles) return;
    int ct = g % nx;
    int col0 = ct * 128;
    int row0 = (g / nx) * 128;

    phase_stagger(bid);

    int t = threadIdx.x;
    int w = t >> 6, lane = t & 63;
    int wm = (w & 3) * 32, wn = (w >> 2) * 64;   // 8 waves = 4M x 2N
    int fr = lane & 15;
    int fq = lane >> 4, fq8 = fq * 8;

    int srow = t >> 2;
    int scol = (t & 3) << 3;
    int lrow = w << 4;

    f32x4 acc[2][4];
    #pragma unroll
    for (int i = 0; i < 2; i++)
        #pragma unroll
        for (int j = 0; j < 4; j++) acc[i][j] = (f32x4){0.f, 0.f, 0.f, 0.f};

    for (int k0 = 0; k0 < K; k0 += 64) {
        if (k0) __syncthreads();
        {
            int ga = row0 + srow; if (ga > M - 1) ga = M - 1;
            int gb = col0 + srow;
            #pragma unroll
            for (int kk = 0; kk < 2; ++kk) {
                int kc = k0 + kk * 32 + scol;
                gload_lds16(Ahi + (size_t)ga * K + kc, &sm[0][kk][lrow][0]);
                gload_lds16(Alo + (size_t)ga * K + kc, &sm[1][kk][lrow][0]);
                gload_lds16(Bhi + (size_t)gb * K + kc, &sm[2][kk][lrow][0]);
                gload_lds16(Blo + (size_t)gb * K + kc, &sm[3][kk][lrow][0]);
            }
        }
        __syncthreads();

        #pragma unroll
        for (int kk = 0; kk < 2; ++kk) {
            half8 bh[4], bl[4];
            #pragma unroll
            for (int ni = 0; ni < 4; ++ni) {
                bh[ni] = *(half8*)&sm[2][kk][wn + ni * 16 + fr][fq8];
                bl[ni] = *(half8*)&sm[3][kk][wn + ni * 16 + fr][fq8];
            }
            #pragma unroll
            for (int mi = 0; mi < 2; ++mi) {
                half8 ah = *(half8*)&sm[0][kk][wm + mi * 16 + fr][fq8];
                half8 al = *(half8*)&sm[1][kk][wm + mi * 16 + fr][fq8];
                #pragma unroll
                for (int ni = 0; ni < 4; ++ni) {
                    acc[mi][ni] = __builtin_amdgcn_mfma_f32_16x16x32_f16(ah, bh[ni], acc[mi][ni], 0, 0, 0);
                    acc[mi][ni] = __builtin_amdgcn_mfma_f32_16x16x32_f16(ah, bl[ni], acc[mi][ni], 0, 0, 0);
                    acc[mi][ni] = __builtin_amdgcn_mfma_f32_16x16x32_f16(al, bh[ni], acc[mi][ni], 0, 0, 0);
                }
            }
        }
    }

    // epilogue: relu(acc+b2) contracted with Wo -> LDS combine -> partial write
    float bv[4];
    float4 wv[4];
    #pragma unroll
    for (int ni = 0; ni < 4; ++ni) {
        int gc = col0 + wn + ni * 16 + fr;
        bv[ni] = bias[gc];
        wv[ni] = *(const float4*)(Wo + (size_t)gc * 4);
    }
    #pragma unroll
    for (int mi = 0; mi < 2; ++mi) {
        #pragma unroll
        for (int r = 0; r < 4; ++r) {
            int row = wm + mi * 16 + fq * 4 + r;
            float o0 = 0.f, o1 = 0.f, o2 = 0.f, o3 = 0.f;
            #pragma unroll
            for (int ni = 0; ni < 4; ++ni) {
                float v = acc[mi][ni][r] + bv[ni];
                v = (v > 0.f) ? v : 0.f;
                o0 += v * wv[ni].x; o1 += v * wv[ni].y;
                o2 += v * wv[ni].z; o3 += v * wv[ni].w;
            }
            #pragma unroll
            for (int off = 1; off < 16; off <<= 1) {
                o0 += __shfl_xor(o0, off); o1 += __shfl_xor(o1, off);
                o2 += __shfl_xor(o2, off); o3 += __shfl_xor(o3, off);
            }
            if (fr == 0) sacc[w >> 2][row] = (float4){o0, o1, o2, o3};
        }
    }
    __syncthreads();
    if (t < 128) {
        int gr = row0 + t;
        if (gr < M) {
            float4 s0 = sacc[0][t], s1 = sacc[1][t];
            float4 o = (float4){s0.x + s1.x, s0.y + s1.y, s0.z + s1.z, s0.w + s1.w};
            *(float4*)(partial + ((size_t)ct * M + gr) * 4) = o;
        }
    }
}

// ---------------- reduce 4 col-tile partials -> out (adds bo) ----------------
__global__ __launch_bounds__(256) void k_headred(const float* __restrict__ partial,
                                                 const float* __restrict__ bo,
                                                 float* __restrict__ out, int M) {
    int r = blockIdx.x * 256 + threadIdx.x;
    if (r >= M) return;
    float4 a = *(const float4*)(partial + ((size_t)0 * M + r) * 4);
    float4 b = *(const float4*)(partial + ((size_t)1 * M + r) * 4);
    float4 c = *(const float4*)(partial + ((size_t)2 * M + r) * 4);
    float4 d = *(const float4*)(partial + ((size_t)3 * M + r) * 4);
    float4 o;
    o.x = a.x + b.x + c.x + d.x + bo[0];
    o.y = a.y + b.y + c.y + d.y + bo[1];
    o.z = a.z + b.z + c.z + d.z + bo[2];
    o.w = a.w + b.w + c.w + d.w + bo[3];
    *(float4*)(out + (size_t)r * 4) = o;
}

extern "C" void kernel_launch(void* const* d_in, const int* in_sizes, int n_in,
                              void* d_out, int out_size, void* d_ws, size_t ws_size,
                              hipStream_t stream) {
    const float* x    = (const float*)d_in[0];
    const int*   eidx = (const int*)d_in[1];
    const float* cW   = (const float*)d_in[2];
    const float* caS  = (const float*)d_in[3];
    const float* caD  = (const float*)d_in[4];
    const float* cB   = (const float*)d_in[5];
    const float* W0   = (const float*)d_in[6];
    const float* b0   = (const float*)d_in[7];
    const float* W1   = (const float*)d_in[8];
    const float* b1   = (const float*)d_in[9];
    const float* W2   = (const float*)d_in[10];
    const float* b2   = (const float*)d_in[11];
    const float* Wo   = (const float*)d_in[12];
    const float* bo   = (const float*)d_in[13];
    (void)in_sizes; (void)n_in; (void)out_size;

    const int* esrc = eidx;
    const int* edst = eidx + NE;
    float* out = (float*)d_out;

    // ---- workspace bump allocator (256B aligned) ----
    char* w = (char*)d_ws;
    auto alloc = [&](size_t bytes) -> char* {
        char* p = w;
        w += (bytes + 255) & ~(size_t)255;
        return p;
    };
    _Float16* x0h  = (_Float16*)alloc((size_t)NN * 128 * 2);
    _Float16* x0l  = (_Float16*)alloc((size_t)NN * 128 * 2);
    _Float16* xh   = (_Float16*)alloc((size_t)NN * 128 * 2);
    _Float16* xl   = (_Float16*)alloc((size_t)NN * 128 * 2);
    _Float16* hbuf = (_Float16*)alloc((size_t)NN * 128 * 2);   // f16 (R17)
    float* ssrc    = (float*)alloc((size_t)NN * 4);
    float* sdst    = (float*)alloc((size_t)NN * 4);
    int*   counts  = (int*)  alloc((size_t)NN * 4);
    int*   offs    = (int*)  alloc((size_t)(NN + 1) * 4);
    int*   cursor  = (int*)  alloc((size_t)NN * 4);
    int*   csr     = (int*)  alloc((size_t)NET * 4);
    int*   part    = (int*)  alloc((size_t)SCAN_NB * 4);
    _Float16* cwh  = (_Float16*)alloc(3 * 128 * 128 * 2);
    _Float16* cwl  = (_Float16*)alloc(3 * 128 * 128 * 2);
    _Float16* w0h  = (_Float16*)alloc(512 * 128 * 2);
    _Float16* w0l  = (_Float16*)alloc(512 * 128 * 2);
    _Float16* w1h  = (_Float16*)alloc(512 * 512 * 2);
    _Float16* w1l  = (_Float16*)alloc(512 * 512 * 2);
    _Float16* w2h  = (_Float16*)alloc(512 * 512 * 2);
    _Float16* w2l  = (_Float16*)alloc(512 * 512 * 2);
    float* hpart   = (float*)alloc((size_t)4 * NN * 4 * 4);   // head partials [4][NN][4]

    size_t used = (size_t)(w - (char*)d_ws);
    size_t rem = (ws_size > used) ? (ws_size - used) : 0;
    int chunk = (int)(rem / (4 * 512 * sizeof(_Float16)));
    if (chunk > NN) chunk = NN;
    if (chunk > 128) chunk &= ~127;
    if (chunk < 1) chunk = 1;
    _Float16* Y0h = (_Float16*)alloc((size_t)chunk * 512 * 2);
    _Float16* Y0l = (_Float16*)alloc((size_t)chunk * 512 * 2);
    _Float16* Y1h = (_Float16*)alloc((size_t)chunk * 512 * 2);
    _Float16* Y1l = (_Float16*)alloc((size_t)chunk * 512 * 2);

    auto gemm = [&](const _Float16* Ah, const _Float16* Al,
                    const _Float16* Bh, const _Float16* Bl,
                    const float* bias, float* Cf, _Float16* Ch, _Float16* Cl,
                    int M, int N, int K, int relu, int split) {
        int nx = N / 128;
        int ntiles = nx * ((M + 127) / 128);
        int nb = ((ntiles + 7) / 8) * 8;
        k_mgemm<<<nb, 512, 0, stream>>>(Ah, Al, Bh, Bl, bias, Cf, Ch, Cl,
                                        M, N, K, relu, split, nx, ntiles);
    };

    // ---- prep: split x, transpose+split weights ----
    k_split<<<2048, 256, 0, stream>>>(x, x0h, x0l, NN * 128);
    for (int L = 0; L < 3; ++L)
        k_prepw<<<dim3(128 / 32, 128 / 32), 256, 0, stream>>>(
            cW + (size_t)L * 128 * 128, cwh + (size_t)L * 128 * 128, cwl + (size_t)L * 128 * 128, 128, 128);
    k_prepw<<<dim3(512 / 32, 128 / 32), 256, 0, stream>>>(W0, w0h, w0l, 128, 512);
    k_prepw<<<dim3(512 / 32, 512 / 32), 256, 0, stream>>>(W1, w1h, w1l, 512, 512);
    k_prepw<<<dim3(512 / 32, 512 / 32), 256, 0, stream>>>(W2, w2h, w2l, 512, 512);

    // ---- build CSR once ----
    hipMemsetAsync(counts, 0, (size_t)NN * 4, stream);
    int eblocks = (NET + 255) / 256;
    k_count <<<eblocks, 256, 0, stream>>>(edst, counts);
    k_scan1 <<<SCAN_NB, 256, 0, stream>>>(counts, part);
    k_scan2 <<<1, 256, 0, stream>>>(part, offs);
    k_scan3 <<<SCAN_NB, 256, 0, stream>>>(counts, part, offs, cursor);
    k_scatter<<<eblocks, 256, 0, stream>>>(esrc, edst, cursor, csr);

    // ---- 3 GAT layers (GEMM fused with attention scalars) ----
    int gat_tiles = (NN + 127) / 128;
    int gat_nb = ((gat_tiles + 7) / 8) * 8;
    for (int L = 0; L < 3; ++L) {
        const _Float16* Ah = (L == 0) ? x0h : xh;
        const _Float16* Al = (L == 0) ? x0l : xl;
        k_mgemm_gat<<<gat_nb, 512, 0, stream>>>(
            Ah, Al, cwh + (size_t)L * 128 * 128, cwl + (size_t)L * 128 * 128,
            caS + L * 128, caD + L * 128, hbuf, ssrc, sdst, NN, gat_tiles);
        k_aggregate<<<NN / 4, 256, 0, stream>>>(hbuf, ssrc, sdst, offs, csr, cB + L * 128, xh, xl);
    }

    // ---- MLP head (chunked over nodes; gemm2 fused with output head) ----
    for (int m0 = 0; m0 < NN; m0 += chunk) {
        int cm = imin(chunk, NN - m0);
        gemm(xh + (size_t)m0 * 128, xl + (size_t)m0 * 128, w0h, w0l, b0,
             nullptr, Y0h, Y0l, cm, 512, 128, 1, 1);
        gemm(Y0h, Y0l, w1h, w1l, b1, nullptr, Y1h, Y1l, cm, 512, 512, 1, 1);
        int nx = 4;
        int ntiles = nx * ((cm + 127) / 128);
        int nb = ((ntiles + 7) / 8) * 8;
        k_mgemm_head<<<nb, 512, 0, stream>>>(Y1h, Y1l, w2h, w2l, b2, Wo,
                                             hpart, cm, 512, nx, ntiles);
        k_headred<<<(cm + 255) / 256, 256, 0, stream>>>(hpart, bo, out + (size_t)m0 * 4, cm);
    }
}

// Round 15
// 590.701 us; speedup vs baseline: 1.0861x; 1.0572x over previous
//
#include <hip/hip_runtime.h>
#include <hip/hip_bf16.h>

#define NN 50000
#define NE 800000
#define NET (NE + NN)
#define SCAN_NB ((NN + 255) / 256)   // 196

static inline int imin(int a, int b) { return a < b ? a : b; }

typedef _Float16 half8 __attribute__((ext_vector_type(8)));
typedef _Float16 half2v __attribute__((ext_vector_type(2)));
typedef float f32x4 __attribute__((ext_vector_type(4)));

// ---------------- CSR build (graph constant across layers) ----------------
__global__ void k_count(const int* __restrict__ edst, int* __restrict__ counts) {
    int e = blockIdx.x * blockDim.x + threadIdx.x;
    if (e >= NET) return;
    int d = (e < NE) ? edst[e] : (e - NE);   // self loops appended
    atomicAdd(&counts[d], 1);
}

__global__ __launch_bounds__(256) void k_scan1(const int* __restrict__ counts,
                                               int* __restrict__ part) {
    __shared__ int s[256];
    int t = threadIdx.x, i = blockIdx.x * 256 + t;
    s[t] = (i < NN) ? counts[i] : 0;
    __syncthreads();
    for (int off = 128; off > 0; off >>= 1) {
        if (t < off) s[t] += s[t + off];
        __syncthreads();
    }
    if (t == 0) part[blockIdx.x] = s[0];
}

__global__ __launch_bounds__(256) void k_scan2(int* __restrict__ part, int* __restrict__ offs) {
    __shared__ int s[256];
    int t = threadIdx.x;
    int v = (t < SCAN_NB) ? part[t] : 0;
    s[t] = v;
    __syncthreads();
    for (int off = 1; off < 256; off <<= 1) {
        int a = (t >= off) ? s[t - off] : 0;
        __syncthreads();
        s[t] += a;
        __syncthreads();
    }
    if (t < SCAN_NB) part[t] = s[t] - v;     // exclusive block offsets
    if (t == 255) offs[NN] = s[255];         // total (= NET)
}

__global__ __launch_bounds__(256) void k_scan3(const int* __restrict__ counts,
                                               const int* __restrict__ part,
                                               int* __restrict__ offs, int* __restrict__ cursor) {
    __shared__ int s[256];
    int t = threadIdx.x, i = blockIdx.x * 256 + t;
    int v = (i < NN) ? counts[i] : 0;
    s[t] = v;
    __syncthreads();
    for (int off = 1; off < 256; off <<= 1) {
        int a = (t >= off) ? s[t - off] : 0;
        __syncthreads();
        s[t] += a;
        __syncthreads();
    }
    if (i < NN) {
        int e = part[blockIdx.x] + s[t] - v;
        offs[i] = e;
        cursor[i] = e;
    }
}

__global__ void k_scatter(const int* __restrict__ esrc, const int* __restrict__ edst,
                          int* __restrict__ cursor, int* __restrict__ csr_src) {
    int e = blockIdx.x * blockDim.x + threadIdx.x;
    if (e >= NET) return;
    int s, d;
    if (e < NE) { s = esrc[e]; d = edst[e]; } else { s = e - NE; d = s; }
    int pos = atomicAdd(&cursor[d], 1);
    csr_src[pos] = s;
}

// ---------------- split fp32 -> f16 hi/lo pair ----------------
__global__ void k_split(const float* __restrict__ in, _Float16* __restrict__ hi,
                        _Float16* __restrict__ lo, int n) {
    int i = blockIdx.x * blockDim.x + threadIdx.x;
    int st = gridDim.x * blockDim.x;
    for (; i < n; i += st) {
        float v = in[i];
        _Float16 h = (_Float16)v;
        hi[i] = h;
        lo[i] = (_Float16)(v - (float)h);
    }
}

// ---------------- transpose + split weights: W[K][N] -> T[N][K] hi/lo (LDS-tiled) ----
__global__ __launch_bounds__(256) void k_prepw(const float* __restrict__ W,
                                               _Float16* __restrict__ Th,
                                               _Float16* __restrict__ Tl, int K, int N) {
    __shared__ float tile[32][33];
    int tx = threadIdx.x & 31, ty = threadIdx.x >> 5;
    int n0 = blockIdx.x * 32, k0 = blockIdx.y * 32;
    #pragma unroll
    for (int r = ty; r < 32; r += 8)
        tile[r][tx] = W[(size_t)(k0 + r) * N + n0 + tx];   // coalesced read
    __syncthreads();
    #pragma unroll
    for (int r = ty; r < 32; r += 8) {
        int n = n0 + r, k = k0 + tx;
        float v = tile[tx][r];
        _Float16 h = (_Float16)v;
        Th[(size_t)n * K + k] = h;                          // coalesced 64B segments
        Tl[(size_t)n * K + k] = (_Float16)(v - (float)h);
    }
}

// ---------------- fused segment-softmax + aggregate + bias + leaky ----------------
// R17: hbuf f16. R23: 8-edge unroll + split accumulators (WIN, wall -15µs).
__global__ void k_aggregate(const _Float16* __restrict__ h, const float* __restrict__ s_src,
                            const float* __restrict__ s_dst, const int* __restrict__ offs,
                            const int* __restrict__ csr_src, const float* __restrict__ bias,
                            _Float16* __restrict__ xh, _Float16* __restrict__ xl) {
    int node = blockIdx.x * 4 + (threadIdx.x >> 6);
    int lane = threadIdx.x & 63;
    if (node >= NN) return;
    int p = offs[node], pe = offs[node + 1];
    float sd = s_dst[node];
    float den0 = 0.f, den1 = 0.f;
    float a00 = 0.f, a01 = 0.f, a10 = 0.f, a11 = 0.f;
    for (; p + 8 <= pe; p += 8) {
        int s0 = csr_src[p + 0], s1 = csr_src[p + 1];
        int s2 = csr_src[p + 2], s3 = csr_src[p + 3];
        int s4 = csr_src[p + 4], s5 = csr_src[p + 5];
        int s6 = csr_src[p + 6], s7 = csr_src[p + 7];
        float e0 = s_src[s0] + sd, e1 = s_src[s1] + sd;
        float e2 = s_src[s2] + sd, e3 = s_src[s3] + sd;
        float e4 = s_src[s4] + sd, e5 = s_src[s5] + sd;
        float e6 = s_src[s6] + sd, e7 = s_src[s7] + sd;
        half2v a0 = *((const half2v*)(h + (size_t)s0 * 128) + lane);
        half2v a1 = *((const half2v*)(h + (size_t)s1 * 128) + lane);
        half2v a2 = *((const half2v*)(h + (size_t)s2 * 128) + lane);
        half2v a3 = *((const half2v*)(h + (size_t)s3 * 128) + lane);
        half2v a4 = *((const half2v*)(h + (size_t)s4 * 128) + lane);
        half2v a5 = *((const half2v*)(h + (size_t)s5 * 128) + lane);
        half2v a6 = *((const half2v*)(h + (size_t)s6 * 128) + lane);
        half2v a7 = *((const half2v*)(h + (size_t)s7 * 128) + lane);
        e0 = (e0 > 0.f) ? e0 : 0.2f * e0;  float w0 = __expf(e0);
        e1 = (e1 > 0.f) ? e1 : 0.2f * e1;  float w1 = __expf(e1);
        e2 = (e2 > 0.f) ? e2 : 0.2f * e2;  float w2 = __expf(e2);
        e3 = (e3 > 0.f) ? e3 : 0.2f * e3;  float w3 = __expf(e3);
        e4 = (e4 > 0.f) ? e4 : 0.2f * e4;  float w4 = __expf(e4);
        e5 = (e5 > 0.f) ? e5 : 0.2f * e5;  float w5 = __expf(e5);
        e6 = (e6 > 0.f) ? e6 : 0.2f * e6;  float w6 = __expf(e6);
        e7 = (e7 > 0.f) ? e7 : 0.2f * e7;  float w7 = __expf(e7);
        den0 += (w0 + w1) + (w2 + w3);
        den1 += (w4 + w5) + (w6 + w7);
        a00 += w0 * (float)a0[0] + w1 * (float)a1[0] + w2 * (float)a2[0] + w3 * (float)a3[0];
        a01 += w0 * (float)a0[1] + w1 * (float)a1[1] + w2 * (float)a2[1] + w3 * (float)a3[1];
        a10 += w4 * (float)a4[0] + w5 * (float)a5[0] + w6 * (float)a6[0] + w7 * (float)a7[0];
        a11 += w4 * (float)a4[1] + w5 * (float)a5[1] + w6 * (float)a6[1] + w7 * (float)a7[1];
    }
    for (; p + 4 <= pe; p += 4) {
        int s0 = csr_src[p + 0], s1 = csr_src[p + 1];
        int s2 = csr_src[p + 2], s3 = csr_src[p + 3];
        float e0 = s_src[s0] + sd, e1 = s_src[s1] + sd;
        float e2 = s_src[s2] + sd, e3 = s_src[s3] + sd;
        half2v a0 = *((const half2v*)(h + (size_t)s0 * 128) + lane);
        half2v a1 = *((const half2v*)(h + (size_t)s1 * 128) + lane);
        half2v a2 = *((const half2v*)(h + (size_t)s2 * 128) + lane);
        half2v a3 = *((const half2v*)(h + (size_t)s3 * 128) + lane);
        e0 = (e0 > 0.f) ? e0 : 0.2f * e0;  float w0 = __expf(e0);
        e1 = (e1 > 0.f) ? e1 : 0.2f * e1;  float w1 = __expf(e1);
        e2 = (e2 > 0.f) ? e2 : 0.2f * e2;  float w2 = __expf(e2);
        e3 = (e3 > 0.f) ? e3 : 0.2f * e3;  float w3 = __expf(e3);
        den0 += (w0 + w1) + (w2 + w3);
        a00 += w0 * (float)a0[0] + w1 * (float)a1[0] + w2 * (float)a2[0] + w3 * (float)a3[0];
        a01 += w0 * (float)a0[1] + w1 * (float)a1[1] + w2 * (float)a2[1] + w3 * (float)a3[1];
    }
    for (; p < pe; ++p) {
        int src = csr_src[p];
        float e = s_src[src] + sd;
        e = (e > 0.f) ? e : 0.2f * e;
        float wgt = __expf(e);
        den0 += wgt;
        half2v av = *((const half2v*)(h + (size_t)src * 128) + lane);
        a00 += wgt * (float)av[0];
        a01 += wgt * (float)av[1];
    }
    float den = den0 + den1;
    float acc0 = a00 + a10, acc1 = a01 + a11;
    float inv = 1.f / den;                    // self-loop guarantees den > 0
    float2 bv = *((const float2*)bias + lane);
    float v0 = acc0 * inv + bv.x;
    float v1 = acc1 * inv + bv.y;
    v0 = (v0 > 0.f) ? v0 : 0.2f * v0;
    v1 = (v1 > 0.f) ? v1 : 0.2f * v1;
    _Float16 h0 = (_Float16)v0, h1 = (_Float16)v1;
    size_t base = (size_t)node * 128 + 2 * lane;
    *(half2v*)(xh + base) = (half2v){h0, h1};
    *(half2v*)(xl + base) = (half2v){(_Float16)(v0 - (float)h0), (_Float16)(v1 - (float)h1)};
}

// ---------------- shared GEMM machinery (R11 structure + R24 precision cut) ----------
// R18+R19+R21: 8 waves, BK=64 two-subtile, LDS-restage epilogue (measured best).
// R24: MLP activations single-f16. Y0/Y1 store hi only (Alo=nullptr -> 2-term
// MFMA Ah·Bhi + Ah·Blo, -33% MFMA; Clo=nullptr -> 1-pass epilogue, write
// traffic halved). Weights ALWAYS split (B hi+lo); GAT path (3 compounding
// layers) keeps full split. Error model: A-side f16 rounding ~4.9e-4 relative
// per MLP layer; R7 measured f16-h in aggregate = zero absmax change.
__device__ __forceinline__ void gload_lds16(const void* g, void* l) {
    __builtin_amdgcn_global_load_lds(
        (const __attribute__((address_space(1))) void*)g,
        (__attribute__((address_space(3))) void*)l, 16, 0, 0);
}

// per-block phase stagger: hash(bid) -> 0..7 sleeps of ~512cy. ~free, tiny win.
__device__ __forceinline__ void phase_stagger(int bid) {
    int ph = (int)(((unsigned)bid * 2654435761u) >> 29);
    for (int i = 0; i < ph; ++i) __builtin_amdgcn_s_sleep(8);
}

// ---------------- generic split-f16 MFMA GEMM (8-wave, BK=64) ----
// Alo == nullptr -> 2-term MFMA (single-f16 A). Clo == nullptr -> hi-only out.
__global__ __launch_bounds__(512) void k_mgemm(
    const _Float16* __restrict__ Ahi, const _Float16* __restrict__ Alo,
    const _Float16* __restrict__ Bhi, const _Float16* __restrict__ Blo,
    const float* __restrict__ bias, float* __restrict__ Cf,
    _Float16* __restrict__ Chi, _Float16* __restrict__ Clo,
    int M, int N, int K, int relu, int split, int nx, int ntiles)
{
    __shared__ _Float16 sm[4][2][128][32];   // 64 KiB; reused as C tile (first 32 KiB)

    int bid = blockIdx.x;
    int per = (ntiles + 7) >> 3;
    int g = (bid & 7) * per + (bid >> 3);
    if (g >= ntiles) return;
    int col0 = (g % nx) * 128;
    int row0 = (g / nx) * 128;

    phase_stagger(bid);

    int t = threadIdx.x;
    int w = t >> 6, lane = t & 63;
    int wm = (w & 3) * 32, wn = (w >> 2) * 64;   // 8 waves = 4M x 2N, wave tile 32x64
    int fr = lane & 15;
    int fq = lane >> 4, fq8 = fq * 8;

    int srow = t >> 2;                // 0..127
    int scol = (t & 3) << 3;          // halfs
    int lrow = w << 4;                // wave-uniform LDS base row

    f32x4 acc[2][4];
    #pragma unroll
    for (int i = 0; i < 2; i++)
        #pragma unroll
        for (int j = 0; j < 4; j++) acc[i][j] = (f32x4){0.f, 0.f, 0.f, 0.f};

    for (int k0 = 0; k0 < K; k0 += 64) {
        if (k0) __syncthreads();
        {
            int ga = row0 + srow; if (ga > M - 1) ga = M - 1;  // M-tail: dup reads, guarded at store
            int gb = col0 + srow;                               // N % 128 == 0 -> in range
            #pragma unroll
            for (int kk = 0; kk < 2; ++kk) {
                int kc = k0 + kk * 32 + scol;
                gload_lds16(Ahi + (size_t)ga * K + kc, &sm[0][kk][lrow][0]);
                if (Alo) gload_lds16(Alo + (size_t)ga * K + kc, &sm[1][kk][lrow][0]);
                gload_lds16(Bhi + (size_t)gb * K + kc, &sm[2][kk][lrow][0]);
                gload_lds16(Blo + (size_t)gb * K + kc, &sm[3][kk][lrow][0]);
            }
        }
        __syncthreads();   // drains vmcnt -> gload_lds stores visible to all waves

        #pragma unroll
        for (int kk = 0; kk < 2; ++kk) {
            half8 bh[4], bl[4];
            #pragma unroll
            for (int ni = 0; ni < 4; ++ni) {
                bh[ni] = *(half8*)&sm[2][kk][wn + ni * 16 + fr][fq8];
                bl[ni] = *(half8*)&sm[3][kk][wn + ni * 16 + fr][fq8];
            }
            #pragma unroll
            for (int mi = 0; mi < 2; ++mi) {
                half8 ah = *(half8*)&sm[0][kk][wm + mi * 16 + fr][fq8];
                #pragma unroll
                for (int ni = 0; ni < 4; ++ni) {
                    acc[mi][ni] = __builtin_amdgcn_mfma_f32_16x16x32_f16(ah, bh[ni], acc[mi][ni], 0, 0, 0);
                    acc[mi][ni] = __builtin_amdgcn_mfma_f32_16x16x32_f16(ah, bl[ni], acc[mi][ni], 0, 0, 0);
                }
                if (Alo) {
                    half8 al = *(half8*)&sm[1][kk][wm + mi * 16 + fr][fq8];
                    #pragma unroll
                    for (int ni = 0; ni < 4; ++ni)
                        acc[mi][ni] = __builtin_amdgcn_mfma_f32_16x16x32_f16(al, bh[ni], acc[mi][ni], 0, 0, 0);
                }
            }
        }
    }

    float bv[4];
    #pragma unroll
    for (int ni = 0; ni < 4; ++ni)
        bv[ni] = bias ? bias[col0 + wn + ni * 16 + fr] : 0.f;

    if (split) {
        // R19 epilogue: restage C via LDS -> 16B coalesced stores.
        // pass 0: hi; pass 1 (only if Clo): lo residual.
        _Float16* sc = &sm[0][0][0][0];   // [128][128] overlay (32 KiB)
        int npass = Clo ? 2 : 1;
        for (int pass = 0; pass < npass; ++pass) {
            __syncthreads();
            #pragma unroll
            for (int mi = 0; mi < 2; ++mi) {
                #pragma unroll
                for (int ni = 0; ni < 4; ++ni) {
                    #pragma unroll
                    for (int r = 0; r < 4; ++r) {
                        int row = wm + mi * 16 + fq * 4 + r;
                        int col = wn + ni * 16 + fr;
                        float v = acc[mi][ni][r] + bv[ni];
                        if (relu) v = (v > 0.f) ? v : 0.f;
                        _Float16 hh = (_Float16)v;
                        sc[row * 128 + col] = pass ? (_Float16)(v - (float)hh) : hh;
                    }
                }
            }
            __syncthreads();
            _Float16* dst = pass ? Clo : Chi;
            #pragma unroll
            for (int pp = 0; pp < 4; ++pp) {
                int idx = t + pp * 512;
                int row = idx >> 4, seg = idx & 15;
                int gr = row0 + row;
                if (gr < M)
                    *(half8*)(dst + (size_t)gr * N + col0 + seg * 8) =
                        *(half8*)&sc[row * 128 + seg * 8];
            }
        }
    } else {
        #pragma unroll
        for (int ni = 0; ni < 4; ++ni) {
            #pragma unroll
            for (int mi = 0; mi < 2; ++mi) {
                #pragma unroll
                for (int r = 0; r < 4; ++r) {
                    int gr = row0 + wm + mi * 16 + fq * 4 + r;
                    if (gr >= M) continue;
                    float v = acc[mi][ni][r] + bv[ni];
                    if (relu) v = (v > 0.f) ? v : 0.f;
                    Cf[(size_t)gr * N + col0 + wn + ni * 16 + fr] = v;
                }
            }
        }
    }
}

// ---------------- GAT GEMM fused with attention scalars (N=K=128, 8-wave BK=64) ----
// Unchanged (full 3-term split — 3 compounding layers keep precision).
__global__ __launch_bounds__(512) void k_mgemm_gat(
    const _Float16* __restrict__ Ahi, const _Float16* __restrict__ Alo,
    const _Float16* __restrict__ Bhi, const _Float16* __restrict__ Blo,
    const float* __restrict__ a_src, const float* __restrict__ a_dst,
    _Float16* __restrict__ hbuf, float* __restrict__ s_src, float* __restrict__ s_dst,
    int M, int ntiles)
{
    __shared__ _Float16 sm[4][2][128][32];   // 64 KiB; reused as hbuf C tile
    __shared__ float sps[2][128], spd[2][128];

    const int K = 128;
    int bid = blockIdx.x;
    int per = (ntiles + 7) >> 3;
    int g = (bid & 7) * per + (bid >> 3);
    if (g >= ntiles) return;
    int row0 = g * 128;                    // nx == 1 (N = 128)

    int t = threadIdx.x;
    int w = t >> 6, lane = t & 63;
    int wm = (w & 3) * 32, wn = (w >> 2) * 64;   // 8 waves = 4M x 2N
    int fr = lane & 15;
    int fq = lane >> 4, fq8 = fq * 8;
    int wnIdx = w >> 2;

    int srow = t >> 2;
    int scol = (t & 3) << 3;
    int lrow = w << 4;

    f32x4 acc[2][4];
    #pragma unroll
    for (int i = 0; i < 2; i++)
        #pragma unroll
        for (int j = 0; j < 4; j++) acc[i][j] = (f32x4){0.f, 0.f, 0.f, 0.f};

    for (int k0 = 0; k0 < K; k0 += 64) {
        if (k0) __syncthreads();
        {
            int ga = row0 + srow; if (ga > M - 1) ga = M - 1;
            int gb = srow;                                    // col0 = 0, N = 128
            #pragma unroll
            for (int kk = 0; kk < 2; ++kk) {
                int kc = k0 + kk * 32 + scol;
                gload_lds16(Ahi + (size_t)ga * K + kc, &sm[0][kk][lrow][0]);
                gload_lds16(Alo + (size_t)ga * K + kc, &sm[1][kk][lrow][0]);
                gload_lds16(Bhi + (size_t)gb * K + kc, &sm[2][kk][lrow][0]);
                gload_lds16(Blo + (size_t)gb * K + kc, &sm[3][kk][lrow][0]);
            }
        }
        __syncthreads();

        #pragma unroll
        for (int kk = 0; kk < 2; ++kk) {
            half8 bh[4], bl[4];
            #pragma unroll
            for (int ni = 0; ni < 4; ++ni) {
                bh[ni] = *(half8*)&sm[2][kk][wn + ni * 16 + fr][fq8];
                bl[ni] = *(half8*)&sm[3][kk][wn + ni * 16 + fr][fq8];
            }
            #pragma unroll
            for (int mi = 0; mi < 2; ++mi) {
                half8 ah = *(half8*)&sm[0][kk][wm + mi * 16 + fr][fq8];
                half8 al = *(half8*)&sm[1][kk][wm + mi * 16 + fr][fq8];
                #pragma unroll
                for (int ni = 0; ni < 4; ++ni) {
                    acc[mi][ni] = __builtin_amdgcn_mfma_f32_16x16x32_f16(ah, bh[ni], acc[mi][ni], 0, 0, 0);
                    acc[mi][ni] = __builtin_amdgcn_mfma_f32_16x16x32_f16(ah, bl[ni], acc[mi][ni], 0, 0, 0);
                    acc[mi][ni] = __builtin_amdgcn_mfma_f32_16x16x32_f16(al, bh[ni], acc[mi][ni], 0, 0, 0);
                }
            }
        }
    }

    // epilogue: scalar dots + restage hbuf via LDS
    float asv[4], adv[4];
    #pragma unroll
    for (int ni = 0; ni < 4; ++ni) {
        int gc = wn + ni * 16 + fr;
        asv[ni] = a_src[gc];
        adv[ni] = a_dst[gc];
    }
    __syncthreads();   // all waves done reading sm (K-loop) before overwrite
    _Float16* sc = &sm[0][0][0][0];   // [128][128]
    #pragma unroll
    for (int mi = 0; mi < 2; ++mi) {
        #pragma unroll
        for (int r = 0; r < 4; ++r) {
            int row = wm + mi * 16 + fq * 4 + r;
            float vps = 0.f, vpd = 0.f;
            #pragma unroll
            for (int ni = 0; ni < 4; ++ni) {
                float v = acc[mi][ni][r];
                vps += v * asv[ni];
                vpd += v * adv[ni];
                sc[row * 128 + wn + ni * 16 + fr] = (_Float16)v;
            }
            #pragma unroll
            for (int off = 1; off < 16; off <<= 1) {
                vps += __shfl_xor(vps, off);
                vpd += __shfl_xor(vpd, off);
            }
            if (fr == 0) { sps[wnIdx][row] = vps; spd[wnIdx][row] = vpd; }
        }
    }
    __syncthreads();
    if (t < 128) {
        int gr = row0 + t;
        if (gr < M) {
            s_src[gr] = sps[0][t] + sps[1][t];
            s_dst[gr] = spd[0][t] + spd[1][t];
        }
    }
    #pragma unroll
    for (int pp = 0; pp < 4; ++pp) {
        int idx = t + pp * 512;
        int row = idx >> 4, seg = idx & 15;
        int gr = row0 + row;
        if (gr < M)
            *(half8*)(hbuf + (size_t)gr * 128 + seg * 8) = *(half8*)&sc[row * 128 + seg * 8];
    }
}

// ---------------- gemm2 fused with MLP head (N=512, 8-wave BK=64, partials out) -----
// R24: A = Y1 single-f16 -> 2-term MFMA (Alo removed).
__global__ __launch_bounds__(512) void k_mgemm_head(
    const _Float16* __restrict__ Ahi,
    const _Float16* __restrict__ Bhi, const _Float16* __restrict__ Blo,
    const float* __restrict__ bias, const float* __restrict__ Wo,
    float* __restrict__ partial,
    int M, int K, int nx, int ntiles)
{
    __shared__ _Float16 sm[3][2][128][32];   // 48 KiB (A, Bhi, Blo)
    __shared__ float4 sacc[2][128];          // 4 KiB: per-wn-half row partials

    int bid = blockIdx.x;
    int per = (ntiles + 7) >> 3;
    int g = (bid & 7) * per + (bid >> 3);
    if (g >= ntiles) return;
    int ct = g % nx;
    int col0 = ct * 128;
    int row0 = (g / nx) * 128;

    phase_stagger(bid);

    int t = threadIdx.x;
    int w = t >> 6, lane = t & 63;
    int wm = (w & 3) * 32, wn = (w >> 2) * 64;   // 8 waves = 4M x 2N
    int fr = lane & 15;
    int fq = lane >> 4, fq8 = fq * 8;

    int srow = t >> 2;
    int scol = (t & 3) << 3;
    int lrow = w << 4;

    f32x4 acc[2][4];
    #pragma unroll
    for (int i = 0; i < 2; i++)
        #pragma unroll
        for (int j = 0; j < 4; j++) acc[i][j] = (f32x4){0.f, 0.f, 0.f, 0.f};

    for (int k0 = 0; k0 < K; k0 += 64) {
        if (k0) __syncthreads();
        {
            int ga = row0 + srow; if (ga > M - 1) ga = M - 1;
            int gb = col0 + srow;
            #pragma unroll
            for (int kk = 0; kk < 2; ++kk) {
                int kc = k0 + kk * 32 + scol;
                gload_lds16(Ahi + (size_t)ga * K + kc, &sm[0][kk][lrow][0]);
                gload_lds16(Bhi + (size_t)gb * K + kc, &sm[1][kk][lrow][0]);
                gload_lds16(Blo + (size_t)gb * K + kc, &sm[2][kk][lrow][0]);
            }
        }
        __syncthreads();

        #pragma unroll
        for (int kk = 0; kk < 2; ++kk) {
            half8 bh[4], bl[4];
            #pragma unroll
            for (int ni = 0; ni < 4; ++ni) {
                bh[ni] = *(half8*)&sm[1][kk][wn + ni * 16 + fr][fq8];
                bl[ni] = *(half8*)&sm[2][kk][wn + ni * 16 + fr][fq8];
            }
            #pragma unroll
            for (int mi = 0; mi < 2; ++mi) {
                half8 ah = *(half8*)&sm[0][kk][wm + mi * 16 + fr][fq8];
                #pragma unroll
                for (int ni = 0; ni < 4; ++ni) {
                    acc[mi][ni] = __builtin_amdgcn_mfma_f32_16x16x32_f16(ah, bh[ni], acc[mi][ni], 0, 0, 0);
                    acc[mi][ni] = __builtin_amdgcn_mfma_f32_16x16x32_f16(ah, bl[ni], acc[mi][ni], 0, 0, 0);
                }
            }
        }
    }

    // epilogue: relu(acc+b2) contracted with Wo -> LDS combine -> partial write
    float bv[4];
    float4 wv[4];
    #pragma unroll
    for (int ni = 0; ni < 4; ++ni) {
        int gc = col0 + wn + ni * 16 + fr;
        bv[ni] = bias[gc];
        wv[ni] = *(const float4*)(Wo + (size_t)gc * 4);
    }
    #pragma unroll
    for (int mi = 0; mi < 2; ++mi) {
        #pragma unroll
        for (int r = 0; r < 4; ++r) {
            int row = wm + mi * 16 + fq * 4 + r;
            float o0 = 0.f, o1 = 0.f, o2 = 0.f, o3 = 0.f;
            #pragma unroll
            for (int ni = 0; ni < 4; ++ni) {
                float v = acc[mi][ni][r] + bv[ni];
                v = (v > 0.f) ? v : 0.f;
                o0 += v * wv[ni].x; o1 += v * wv[ni].y;
                o2 += v * wv[ni].z; o3 += v * wv[ni].w;
            }
            #pragma unroll
            for (int off = 1; off < 16; off <<= 1) {
                o0 += __shfl_xor(o0, off); o1 += __shfl_xor(o1, off);
                o2 += __shfl_xor(o2, off); o3 += __shfl_xor(o3, off);
            }
            if (fr == 0) sacc[w >> 2][row] = (float4){o0, o1, o2, o3};
        }
    }
    __syncthreads();
    if (t < 128) {
        int gr = row0 + t;
        if (gr < M) {
            float4 s0 = sacc[0][t], s1 = sacc[1][t];
            float4 o = (float4){s0.x + s1.x, s0.y + s1.y, s0.z + s1.z, s0.w + s1.w};
            *(float4*)(partial + ((size_t)ct * M + gr) * 4) = o;
        }
    }
}

// ---------------- reduce 4 col-tile partials -> out (adds bo) ----------------
__global__ __launch_bounds__(256) void k_headred(const float* __restrict__ partial,
                                                 const float* __restrict__ bo,
                                                 float* __restrict__ out, int M) {
    int r = blockIdx.x * 256 + threadIdx.x;
    if (r >= M) return;
    float4 a = *(const float4*)(partial + ((size_t)0 * M + r) * 4);
    float4 b = *(const float4*)(partial + ((size_t)1 * M + r) * 4);
    float4 c = *(const float4*)(partial + ((size_t)2 * M + r) * 4);
    float4 d = *(const float4*)(partial + ((size_t)3 * M + r) * 4);
    float4 o;
    o.x = a.x + b.x + c.x + d.x + bo[0];
    o.y = a.y + b.y + c.y + d.y + bo[1];
    o.z = a.z + b.z + c.z + d.z + bo[2];
    o.w = a.w + b.w + c.w + d.w + bo[3];
    *(float4*)(out + (size_t)r * 4) = o;
}

extern "C" void kernel_launch(void* const* d_in, const int* in_sizes, int n_in,
                              void* d_out, int out_size, void* d_ws, size_t ws_size,
                              hipStream_t stream) {
    const float* x    = (const float*)d_in[0];
    const int*   eidx = (const int*)d_in[1];
    const float* cW   = (const float*)d_in[2];
    const float* caS  = (const float*)d_in[3];
    const float* caD  = (const float*)d_in[4];
    const float* cB   = (const float*)d_in[5];
    const float* W0   = (const float*)d_in[6];
    const float* b0   = (const float*)d_in[7];
    const float* W1   = (const float*)d_in[8];
    const float* b1   = (const float*)d_in[9];
    const float* W2   = (const float*)d_in[10];
    const float* b2   = (const float*)d_in[11];
    const float* Wo   = (const float*)d_in[12];
    const float* bo   = (const float*)d_in[13];
    (void)in_sizes; (void)n_in; (void)out_size;

    const int* esrc = eidx;
    const int* edst = eidx + NE;
    float* out = (float*)d_out;

    // ---- workspace bump allocator (256B aligned) ----
    char* w = (char*)d_ws;
    auto alloc = [&](size_t bytes) -> char* {
        char* p = w;
        w += (bytes + 255) & ~(size_t)255;
        return p;
    };
    _Float16* x0h  = (_Float16*)alloc((size_t)NN * 128 * 2);
    _Float16* x0l  = (_Float16*)alloc((size_t)NN * 128 * 2);
    _Float16* xh   = (_Float16*)alloc((size_t)NN * 128 * 2);
    _Float16* xl   = (_Float16*)alloc((size_t)NN * 128 * 2);
    _Float16* hbuf = (_Float16*)alloc((size_t)NN * 128 * 2);   // f16 (R17)
    float* ssrc    = (float*)alloc((size_t)NN * 4);
    float* sdst    = (float*)alloc((size_t)NN * 4);
    int*   counts  = (int*)  alloc((size_t)NN * 4);
    int*   offs    = (int*)  alloc((size_t)(NN + 1) * 4);
    int*   cursor  = (int*)  alloc((size_t)NN * 4);
    int*   csr     = (int*)  alloc((size_t)NET * 4);
    int*   part    = (int*)  alloc((size_t)SCAN_NB * 4);
    _Float16* cwh  = (_Float16*)alloc(3 * 128 * 128 * 2);
    _Float16* cwl  = (_Float16*)alloc(3 * 128 * 128 * 2);
    _Float16* w0h  = (_Float16*)alloc(512 * 128 * 2);
    _Float16* w0l  = (_Float16*)alloc(512 * 128 * 2);
    _Float16* w1h  = (_Float16*)alloc(512 * 512 * 2);
    _Float16* w1l  = (_Float16*)alloc(512 * 512 * 2);
    _Float16* w2h  = (_Float16*)alloc(512 * 512 * 2);
    _Float16* w2l  = (_Float16*)alloc(512 * 512 * 2);
    float* hpart   = (float*)alloc((size_t)4 * NN * 4 * 4);   // head partials [4][NN][4]

    size_t used = (size_t)(w - (char*)d_ws);
    size_t rem = (ws_size > used) ? (ws_size - used) : 0;
    int chunk = (int)(rem / (2 * 512 * sizeof(_Float16)));   // Y0h + Y1h only (R24)
    if (chunk > NN) chunk = NN;
    if (chunk > 128) chunk &= ~127;
    if (chunk < 1) chunk = 1;
    _Float16* Y0h = (_Float16*)alloc((size_t)chunk * 512 * 2);
    _Float16* Y1h = (_Float16*)alloc((size_t)chunk * 512 * 2);

    auto gemm = [&](const _Float16* Ah, const _Float16* Al,
                    const _Float16* Bh, const _Float16* Bl,
                    const float* bias, float* Cf, _Float16* Ch, _Float16* Cl,
                    int M, int N, int K, int relu, int split) {
        int nx = N / 128;
        int ntiles = nx * ((M + 127) / 128);
        int nb = ((ntiles + 7) / 8) * 8;
        k_mgemm<<<nb, 512, 0, stream>>>(Ah, Al, Bh, Bl, bias, Cf, Ch, Cl,
                                        M, N, K, relu, split, nx, ntiles);
    };

    // ---- prep: split x, transpose+split weights ----
    k_split<<<2048, 256, 0, stream>>>(x, x0h, x0l, NN * 128);
    for (int L = 0; L < 3; ++L)
        k_prepw<<<dim3(128 / 32, 128 / 32), 256, 0, stream>>>(
            cW + (size_t)L * 128 * 128, cwh + (size_t)L * 128 * 128, cwl + (size_t)L * 128 * 128, 128, 128);
    k_prepw<<<dim3(512 / 32, 128 / 32), 256, 0, stream>>>(W0, w0h, w0l, 128, 512);
    k_prepw<<<dim3(512 / 32, 512 / 32), 256, 0, stream>>>(W1, w1h, w1l, 512, 512);
    k_prepw<<<dim3(512 / 32, 512 / 32), 256, 0, stream>>>(W2, w2h, w2l, 512, 512);

    // ---- build CSR once ----
    hipMemsetAsync(counts, 0, (size_t)NN * 4, stream);
    int eblocks = (NET + 255) / 256;
    k_count <<<eblocks, 256, 0, stream>>>(edst, counts);
    k_scan1 <<<SCAN_NB, 256, 0, stream>>>(counts, part);
    k_scan2 <<<1, 256, 0, stream>>>(part, offs);
    k_scan3 <<<SCAN_NB, 256, 0, stream>>>(counts, part, offs, cursor);
    k_scatter<<<eblocks, 256, 0, stream>>>(esrc, edst, cursor, csr);

    // ---- 3 GAT layers (GEMM fused with attention scalars; full split) ----
    int gat_tiles = (NN + 127) / 128;
    int gat_nb = ((gat_tiles + 7) / 8) * 8;
    for (int L = 0; L < 3; ++L) {
        const _Float16* Ah = (L == 0) ? x0h : xh;
        const _Float16* Al = (L == 0) ? x0l : xl;
        k_mgemm_gat<<<gat_nb, 512, 0, stream>>>(
            Ah, Al, cwh + (size_t)L * 128 * 128, cwl + (size_t)L * 128 * 128,
            caS + L * 128, caD + L * 128, hbuf, ssrc, sdst, NN, gat_tiles);
        k_aggregate<<<NN / 4, 256, 0, stream>>>(hbuf, ssrc, sdst, offs, csr, cB + L * 128, xh, xl);
    }

    // ---- MLP head (R24: single-f16 activations; gemm2 fused with output head) ----
    for (int m0 = 0; m0 < NN; m0 += chunk) {
        int cm = imin(chunk, NN - m0);
        // gemm0: A = x (full split), out Y0 hi-only
        gemm(xh + (size_t)m0 * 128, xl + (size_t)m0 * 128, w0h, w0l, b0,
             nullptr, Y0h, nullptr, cm, 512, 128, 1, 1);
        // gemm1: A = Y0 (single f16, 2-term), out Y1 hi-only
        gemm(Y0h, nullptr, w1h, w1l, b1, nullptr, Y1h, nullptr, cm, 512, 512, 1, 1);
        int nx = 4;
        int ntiles = nx * ((cm + 127) / 128);
        int nb = ((ntiles + 7) / 8) * 8;
        k_mgemm_head<<<nb, 512, 0, stream>>>(Y1h, w2h, w2l, b2, Wo,
                                             hpart, cm, 512, nx, ntiles);
        k_headred<<<(cm + 255) / 256, 256, 0, stream>>>(hpart, bo, out + (size_t)m0 * 4, cm);
    }
}

// Round 16
// 589.843 us; speedup vs baseline: 1.0877x; 1.0015x over previous
//
#include <hip/hip_runtime.h>
#include <hip/hip_bf16.h>

#define NN 50000
#define NE 800000
#define NET (NE + NN)
#define SCAN_NB ((NN + 255) / 256)   // 196

static inline int imin(int a, int b) { return a < b ? a : b; }

typedef _Float16 half8 __attribute__((ext_vector_type(8)));
typedef _Float16 half2v __attribute__((ext_vector_type(2)));
typedef float f32x4 __attribute__((ext_vector_type(4)));

// ---------------- CSR build (graph constant across layers) ----------------
__global__ void k_count(const int* __restrict__ edst, int* __restrict__ counts) {
    int e = blockIdx.x * blockDim.x + threadIdx.x;
    if (e >= NET) return;
    int d = (e < NE) ? edst[e] : (e - NE);   // self loops appended
    atomicAdd(&counts[d], 1);
}

__global__ __launch_bounds__(256) void k_scan1(const int* __restrict__ counts,
                                               int* __restrict__ part) {
    __shared__ int s[256];
    int t = threadIdx.x, i = blockIdx.x * 256 + t;
    s[t] = (i < NN) ? counts[i] : 0;
    __syncthreads();
    for (int off = 128; off > 0; off >>= 1) {
        if (t < off) s[t] += s[t + off];
        __syncthreads();
    }
    if (t == 0) part[blockIdx.x] = s[0];
}

__global__ __launch_bounds__(256) void k_scan2(int* __restrict__ part, int* __restrict__ offs) {
    __shared__ int s[256];
    int t = threadIdx.x;
    int v = (t < SCAN_NB) ? part[t] : 0;
    s[t] = v;
    __syncthreads();
    for (int off = 1; off < 256; off <<= 1) {
        int a = (t >= off) ? s[t - off] : 0;
        __syncthreads();
        s[t] += a;
        __syncthreads();
    }
    if (t < SCAN_NB) part[t] = s[t] - v;     // exclusive block offsets
    if (t == 255) offs[NN] = s[255];         // total (= NET)
}

__global__ __launch_bounds__(256) void k_scan3(const int* __restrict__ counts,
                                               const int* __restrict__ part,
                                               int* __restrict__ offs, int* __restrict__ cursor) {
    __shared__ int s[256];
    int t = threadIdx.x, i = blockIdx.x * 256 + t;
    int v = (i < NN) ? counts[i] : 0;
    s[t] = v;
    __syncthreads();
    for (int off = 1; off < 256; off <<= 1) {
        int a = (t >= off) ? s[t - off] : 0;
        __syncthreads();
        s[t] += a;
        __syncthreads();
    }
    if (i < NN) {
        int e = part[blockIdx.x] + s[t] - v;
        offs[i] = e;
        cursor[i] = e;
    }
}

__global__ void k_scatter(const int* __restrict__ esrc, const int* __restrict__ edst,
                          int* __restrict__ cursor, int* __restrict__ csr_src) {
    int e = blockIdx.x * blockDim.x + threadIdx.x;
    if (e >= NET) return;
    int s, d;
    if (e < NE) { s = esrc[e]; d = edst[e]; } else { s = e - NE; d = s; }
    int pos = atomicAdd(&cursor[d], 1);
    csr_src[pos] = s;
}

// ---------------- split fp32 -> f16 hi/lo pair ----------------
__global__ void k_split(const float* __restrict__ in, _Float16* __restrict__ hi,
                        _Float16* __restrict__ lo, int n) {
    int i = blockIdx.x * blockDim.x + threadIdx.x;
    int st = gridDim.x * blockDim.x;
    for (; i < n; i += st) {
        float v = in[i];
        _Float16 h = (_Float16)v;
        hi[i] = h;
        lo[i] = (_Float16)(v - (float)h);
    }
}

// ---------------- transpose + split weights: W[K][N] -> T[N][K] hi/lo (LDS-tiled) ----
__global__ __launch_bounds__(256) void k_prepw(const float* __restrict__ W,
                                               _Float16* __restrict__ Th,
                                               _Float16* __restrict__ Tl, int K, int N) {
    __shared__ float tile[32][33];
    int tx = threadIdx.x & 31, ty = threadIdx.x >> 5;
    int n0 = blockIdx.x * 32, k0 = blockIdx.y * 32;
    #pragma unroll
    for (int r = ty; r < 32; r += 8)
        tile[r][tx] = W[(size_t)(k0 + r) * N + n0 + tx];   // coalesced read
    __syncthreads();
    #pragma unroll
    for (int r = ty; r < 32; r += 8) {
        int n = n0 + r, k = k0 + tx;
        float v = tile[tx][r];
        _Float16 h = (_Float16)v;
        Th[(size_t)n * K + k] = h;                          // coalesced 64B segments
        Tl[(size_t)n * K + k] = (_Float16)(v - (float)h);
    }
}

// ---------------- fused segment-softmax + aggregate + bias + leaky ----------------
// R17: hbuf f16. R23: 8-edge unroll. R25: x output hi-only (xl dropped —
// R7/R15 measured zero absmax change for identical-class activation cuts);
// write traffic halved.
__global__ void k_aggregate(const _Float16* __restrict__ h, const float* __restrict__ s_src,
                            const float* __restrict__ s_dst, const int* __restrict__ offs,
                            const int* __restrict__ csr_src, const float* __restrict__ bias,
                            _Float16* __restrict__ xh) {
    int node = blockIdx.x * 4 + (threadIdx.x >> 6);
    int lane = threadIdx.x & 63;
    if (node >= NN) return;
    int p = offs[node], pe = offs[node + 1];
    float sd = s_dst[node];
    float den0 = 0.f, den1 = 0.f;
    float a00 = 0.f, a01 = 0.f, a10 = 0.f, a11 = 0.f;
    for (; p + 8 <= pe; p += 8) {
        int s0 = csr_src[p + 0], s1 = csr_src[p + 1];
        int s2 = csr_src[p + 2], s3 = csr_src[p + 3];
        int s4 = csr_src[p + 4], s5 = csr_src[p + 5];
        int s6 = csr_src[p + 6], s7 = csr_src[p + 7];
        float e0 = s_src[s0] + sd, e1 = s_src[s1] + sd;
        float e2 = s_src[s2] + sd, e3 = s_src[s3] + sd;
        float e4 = s_src[s4] + sd, e5 = s_src[s5] + sd;
        float e6 = s_src[s6] + sd, e7 = s_src[s7] + sd;
        half2v a0 = *((const half2v*)(h + (size_t)s0 * 128) + lane);
        half2v a1 = *((const half2v*)(h + (size_t)s1 * 128) + lane);
        half2v a2 = *((const half2v*)(h + (size_t)s2 * 128) + lane);
        half2v a3 = *((const half2v*)(h + (size_t)s3 * 128) + lane);
        half2v a4 = *((const half2v*)(h + (size_t)s4 * 128) + lane);
        half2v a5 = *((const half2v*)(h + (size_t)s5 * 128) + lane);
        half2v a6 = *((const half2v*)(h + (size_t)s6 * 128) + lane);
        half2v a7 = *((const half2v*)(h + (size_t)s7 * 128) + lane);
        e0 = (e0 > 0.f) ? e0 : 0.2f * e0;  float w0 = __expf(e0);
        e1 = (e1 > 0.f) ? e1 : 0.2f * e1;  float w1 = __expf(e1);
        e2 = (e2 > 0.f) ? e2 : 0.2f * e2;  float w2 = __expf(e2);
        e3 = (e3 > 0.f) ? e3 : 0.2f * e3;  float w3 = __expf(e3);
        e4 = (e4 > 0.f) ? e4 : 0.2f * e4;  float w4 = __expf(e4);
        e5 = (e5 > 0.f) ? e5 : 0.2f * e5;  float w5 = __expf(e5);
        e6 = (e6 > 0.f) ? e6 : 0.2f * e6;  float w6 = __expf(e6);
        e7 = (e7 > 0.f) ? e7 : 0.2f * e7;  float w7 = __expf(e7);
        den0 += (w0 + w1) + (w2 + w3);
        den1 += (w4 + w5) + (w6 + w7);
        a00 += w0 * (float)a0[0] + w1 * (float)a1[0] + w2 * (float)a2[0] + w3 * (float)a3[0];
        a01 += w0 * (float)a0[1] + w1 * (float)a1[1] + w2 * (float)a2[1] + w3 * (float)a3[1];
        a10 += w4 * (float)a4[0] + w5 * (float)a5[0] + w6 * (float)a6[0] + w7 * (float)a7[0];
        a11 += w4 * (float)a4[1] + w5 * (float)a5[1] + w6 * (float)a6[1] + w7 * (float)a7[1];
    }
    for (; p + 4 <= pe; p += 4) {
        int s0 = csr_src[p + 0], s1 = csr_src[p + 1];
        int s2 = csr_src[p + 2], s3 = csr_src[p + 3];
        float e0 = s_src[s0] + sd, e1 = s_src[s1] + sd;
        float e2 = s_src[s2] + sd, e3 = s_src[s3] + sd;
        half2v a0 = *((const half2v*)(h + (size_t)s0 * 128) + lane);
        half2v a1 = *((const half2v*)(h + (size_t)s1 * 128) + lane);
        half2v a2 = *((const half2v*)(h + (size_t)s2 * 128) + lane);
        half2v a3 = *((const half2v*)(h + (size_t)s3 * 128) + lane);
        e0 = (e0 > 0.f) ? e0 : 0.2f * e0;  float w0 = __expf(e0);
        e1 = (e1 > 0.f) ? e1 : 0.2f * e1;  float w1 = __expf(e1);
        e2 = (e2 > 0.f) ? e2 : 0.2f * e2;  float w2 = __expf(e2);
        e3 = (e3 > 0.f) ? e3 : 0.2f * e3;  float w3 = __expf(e3);
        den0 += (w0 + w1) + (w2 + w3);
        a00 += w0 * (float)a0[0] + w1 * (float)a1[0] + w2 * (float)a2[0] + w3 * (float)a3[0];
        a01 += w0 * (float)a0[1] + w1 * (float)a1[1] + w2 * (float)a2[1] + w3 * (float)a3[1];
    }
    for (; p < pe; ++p) {
        int src = csr_src[p];
        float e = s_src[src] + sd;
        e = (e > 0.f) ? e : 0.2f * e;
        float wgt = __expf(e);
        den0 += wgt;
        half2v av = *((const half2v*)(h + (size_t)src * 128) + lane);
        a00 += wgt * (float)av[0];
        a01 += wgt * (float)av[1];
    }
    float den = den0 + den1;
    float acc0 = a00 + a10, acc1 = a01 + a11;
    float inv = 1.f / den;                    // self-loop guarantees den > 0
    float2 bv = *((const float2*)bias + lane);
    float v0 = acc0 * inv + bv.x;
    float v1 = acc1 * inv + bv.y;
    v0 = (v0 > 0.f) ? v0 : 0.2f * v0;
    v1 = (v1 > 0.f) ? v1 : 0.2f * v1;
    size_t base = (size_t)node * 128 + 2 * lane;
    *(half2v*)(xh + base) = (half2v){(_Float16)v0, (_Float16)v1};
}

// ---------------- shared GEMM machinery (R11 structure + R24/R25 precision cut) ------
// R18+R19+R21: 8 waves, BK=64 two-subtile, LDS-restage epilogue (measured best).
// R24: MLP activations single-f16 (Y0/Y1 hi-only, 2-term MFMA) — absmax
// unchanged (3rd free cut). R25: GAT L1/L2 + gemm0 A also single-f16 (xl
// dropped). Layer-0 input keeps full x0 split; weights ALWAYS split.
__device__ __forceinline__ void gload_lds16(const void* g, void* l) {
    __builtin_amdgcn_global_load_lds(
        (const __attribute__((address_space(1))) void*)g,
        (__attribute__((address_space(3))) void*)l, 16, 0, 0);
}

// per-block phase stagger: hash(bid) -> 0..7 sleeps of ~512cy. ~free, tiny win.
__device__ __forceinline__ void phase_stagger(int bid) {
    int ph = (int)(((unsigned)bid * 2654435761u) >> 29);
    for (int i = 0; i < ph; ++i) __builtin_amdgcn_s_sleep(8);
}

// ---------------- generic split-f16 MFMA GEMM (8-wave, BK=64) ----
// Alo == nullptr -> 2-term MFMA (single-f16 A). Clo == nullptr -> hi-only out.
__global__ __launch_bounds__(512) void k_mgemm(
    const _Float16* __restrict__ Ahi, const _Float16* __restrict__ Alo,
    const _Float16* __restrict__ Bhi, const _Float16* __restrict__ Blo,
    const float* __restrict__ bias, float* __restrict__ Cf,
    _Float16* __restrict__ Chi, _Float16* __restrict__ Clo,
    int M, int N, int K, int relu, int split, int nx, int ntiles)
{
    __shared__ _Float16 sm[4][2][128][32];   // 64 KiB; reused as C tile (first 32 KiB)

    int bid = blockIdx.x;
    int per = (ntiles + 7) >> 3;
    int g = (bid & 7) * per + (bid >> 3);
    if (g >= ntiles) return;
    int col0 = (g % nx) * 128;
    int row0 = (g / nx) * 128;

    phase_stagger(bid);

    int t = threadIdx.x;
    int w = t >> 6, lane = t & 63;
    int wm = (w & 3) * 32, wn = (w >> 2) * 64;   // 8 waves = 4M x 2N, wave tile 32x64
    int fr = lane & 15;
    int fq = lane >> 4, fq8 = fq * 8;

    int srow = t >> 2;                // 0..127
    int scol = (t & 3) << 3;          // halfs
    int lrow = w << 4;                // wave-uniform LDS base row

    f32x4 acc[2][4];
    #pragma unroll
    for (int i = 0; i < 2; i++)
        #pragma unroll
        for (int j = 0; j < 4; j++) acc[i][j] = (f32x4){0.f, 0.f, 0.f, 0.f};

    for (int k0 = 0; k0 < K; k0 += 64) {
        if (k0) __syncthreads();
        {
            int ga = row0 + srow; if (ga > M - 1) ga = M - 1;  // M-tail: dup reads, guarded at store
            int gb = col0 + srow;                               // N % 128 == 0 -> in range
            #pragma unroll
            for (int kk = 0; kk < 2; ++kk) {
                int kc = k0 + kk * 32 + scol;
                gload_lds16(Ahi + (size_t)ga * K + kc, &sm[0][kk][lrow][0]);
                if (Alo) gload_lds16(Alo + (size_t)ga * K + kc, &sm[1][kk][lrow][0]);
                gload_lds16(Bhi + (size_t)gb * K + kc, &sm[2][kk][lrow][0]);
                gload_lds16(Blo + (size_t)gb * K + kc, &sm[3][kk][lrow][0]);
            }
        }
        __syncthreads();   // drains vmcnt -> gload_lds stores visible to all waves

        #pragma unroll
        for (int kk = 0; kk < 2; ++kk) {
            half8 bh[4], bl[4];
            #pragma unroll
            for (int ni = 0; ni < 4; ++ni) {
                bh[ni] = *(half8*)&sm[2][kk][wn + ni * 16 + fr][fq8];
                bl[ni] = *(half8*)&sm[3][kk][wn + ni * 16 + fr][fq8];
            }
            #pragma unroll
            for (int mi = 0; mi < 2; ++mi) {
                half8 ah = *(half8*)&sm[0][kk][wm + mi * 16 + fr][fq8];
                #pragma unroll
                for (int ni = 0; ni < 4; ++ni) {
                    acc[mi][ni] = __builtin_amdgcn_mfma_f32_16x16x32_f16(ah, bh[ni], acc[mi][ni], 0, 0, 0);
                    acc[mi][ni] = __builtin_amdgcn_mfma_f32_16x16x32_f16(ah, bl[ni], acc[mi][ni], 0, 0, 0);
                }
                if (Alo) {
                    half8 al = *(half8*)&sm[1][kk][wm + mi * 16 + fr][fq8];
                    #pragma unroll
                    for (int ni = 0; ni < 4; ++ni)
                        acc[mi][ni] = __builtin_amdgcn_mfma_f32_16x16x32_f16(al, bh[ni], acc[mi][ni], 0, 0, 0);
                }
            }
        }
    }

    float bv[4];
    #pragma unroll
    for (int ni = 0; ni < 4; ++ni)
        bv[ni] = bias ? bias[col0 + wn + ni * 16 + fr] : 0.f;

    if (split) {
        // R19 epilogue: restage C via LDS -> 16B coalesced stores.
        _Float16* sc = &sm[0][0][0][0];   // [128][128] overlay (32 KiB)
        int npass = Clo ? 2 : 1;
        for (int pass = 0; pass < npass; ++pass) {
            __syncthreads();
            #pragma unroll
            for (int mi = 0; mi < 2; ++mi) {
                #pragma unroll
                for (int ni = 0; ni < 4; ++ni) {
                    #pragma unroll
                    for (int r = 0; r < 4; ++r) {
                        int row = wm + mi * 16 + fq * 4 + r;
                        int col = wn + ni * 16 + fr;
                        float v = acc[mi][ni][r] + bv[ni];
                        if (relu) v = (v > 0.f) ? v : 0.f;
                        _Float16 hh = (_Float16)v;
                        sc[row * 128 + col] = pass ? (_Float16)(v - (float)hh) : hh;
                    }
                }
            }
            __syncthreads();
            _Float16* dst = pass ? Clo : Chi;
            #pragma unroll
            for (int pp = 0; pp < 4; ++pp) {
                int idx = t + pp * 512;
                int row = idx >> 4, seg = idx & 15;
                int gr = row0 + row;
                if (gr < M)
                    *(half8*)(dst + (size_t)gr * N + col0 + seg * 8) =
                        *(half8*)&sc[row * 128 + seg * 8];
            }
        }
    } else {
        #pragma unroll
        for (int ni = 0; ni < 4; ++ni) {
            #pragma unroll
            for (int mi = 0; mi < 2; ++mi) {
                #pragma unroll
                for (int r = 0; r < 4; ++r) {
                    int gr = row0 + wm + mi * 16 + fq * 4 + r;
                    if (gr >= M) continue;
                    float v = acc[mi][ni][r] + bv[ni];
                    if (relu) v = (v > 0.f) ? v : 0.f;
                    Cf[(size_t)gr * N + col0 + wn + ni * 16 + fr] = v;
                }
            }
        }
    }
}

// ---------------- GAT GEMM fused with attention scalars (N=K=128, 8-wave BK=64) ----
// R25: Alo nullable (L1/L2 single-f16 A -> 2-term); L0 keeps full x0 split.
__global__ __launch_bounds__(512) void k_mgemm_gat(
    const _Float16* __restrict__ Ahi, const _Float16* __restrict__ Alo,
    const _Float16* __restrict__ Bhi, const _Float16* __restrict__ Blo,
    const float* __restrict__ a_src, const float* __restrict__ a_dst,
    _Float16* __restrict__ hbuf, float* __restrict__ s_src, float* __restrict__ s_dst,
    int M, int ntiles)
{
    __shared__ _Float16 sm[4][2][128][32];   // 64 KiB; reused as hbuf C tile
    __shared__ float sps[2][128], spd[2][128];

    const int K = 128;
    int bid = blockIdx.x;
    int per = (ntiles + 7) >> 3;
    int g = (bid & 7) * per + (bid >> 3);
    if (g >= ntiles) return;
    int row0 = g * 128;                    // nx == 1 (N = 128)

    int t = threadIdx.x;
    int w = t >> 6, lane = t & 63;
    int wm = (w & 3) * 32, wn = (w >> 2) * 64;   // 8 waves = 4M x 2N
    int fr = lane & 15;
    int fq = lane >> 4, fq8 = fq * 8;
    int wnIdx = w >> 2;

    int srow = t >> 2;
    int scol = (t & 3) << 3;
    int lrow = w << 4;

    f32x4 acc[2][4];
    #pragma unroll
    for (int i = 0; i < 2; i++)
        #pragma unroll
        for (int j = 0; j < 4; j++) acc[i][j] = (f32x4){0.f, 0.f, 0.f, 0.f};

    for (int k0 = 0; k0 < K; k0 += 64) {
        if (k0) __syncthreads();
        {
            int ga = row0 + srow; if (ga > M - 1) ga = M - 1;
            int gb = srow;                                    // col0 = 0, N = 128
            #pragma unroll
            for (int kk = 0; kk < 2; ++kk) {
                int kc = k0 + kk * 32 + scol;
                gload_lds16(Ahi + (size_t)ga * K + kc, &sm[0][kk][lrow][0]);
                if (Alo) gload_lds16(Alo + (size_t)ga * K + kc, &sm[1][kk][lrow][0]);
                gload_lds16(Bhi + (size_t)gb * K + kc, &sm[2][kk][lrow][0]);
                gload_lds16(Blo + (size_t)gb * K + kc, &sm[3][kk][lrow][0]);
            }
        }
        __syncthreads();

        #pragma unroll
        for (int kk = 0; kk < 2; ++kk) {
            half8 bh[4], bl[4];
            #pragma unroll
            for (int ni = 0; ni < 4; ++ni) {
                bh[ni] = *(half8*)&sm[2][kk][wn + ni * 16 + fr][fq8];
                bl[ni] = *(half8*)&sm[3][kk][wn + ni * 16 + fr][fq8];
            }
            #pragma unroll
            for (int mi = 0; mi < 2; ++mi) {
                half8 ah = *(half8*)&sm[0][kk][wm + mi * 16 + fr][fq8];
                #pragma unroll
                for (int ni = 0; ni < 4; ++ni) {
                    acc[mi][ni] = __builtin_amdgcn_mfma_f32_16x16x32_f16(ah, bh[ni], acc[mi][ni], 0, 0, 0);
                    acc[mi][ni] = __builtin_amdgcn_mfma_f32_16x16x32_f16(ah, bl[ni], acc[mi][ni], 0, 0, 0);
                }
                if (Alo) {
                    half8 al = *(half8*)&sm[1][kk][wm + mi * 16 + fr][fq8];
                    #pragma unroll
                    for (int ni = 0; ni < 4; ++ni)
                        acc[mi][ni] = __builtin_amdgcn_mfma_f32_16x16x32_f16(al, bh[ni], acc[mi][ni], 0, 0, 0);
                }
            }
        }
    }

    // epilogue: scalar dots + restage hbuf via LDS
    float asv[4], adv[4];
    #pragma unroll
    for (int ni = 0; ni < 4; ++ni) {
        int gc = wn + ni * 16 + fr;
        asv[ni] = a_src[gc];
        adv[ni] = a_dst[gc];
    }
    __syncthreads();   // all waves done reading sm (K-loop) before overwrite
    _Float16* sc = &sm[0][0][0][0];   // [128][128]
    #pragma unroll
    for (int mi = 0; mi < 2; ++mi) {
        #pragma unroll
        for (int r = 0; r < 4; ++r) {
            int row = wm + mi * 16 + fq * 4 + r;
            float vps = 0.f, vpd = 0.f;
            #pragma unroll
            for (int ni = 0; ni < 4; ++ni) {
                float v = acc[mi][ni][r];
                vps += v * asv[ni];
                vpd += v * adv[ni];
                sc[row * 128 + wn + ni * 16 + fr] = (_Float16)v;
            }
            #pragma unroll
            for (int off = 1; off < 16; off <<= 1) {
                vps += __shfl_xor(vps, off);
                vpd += __shfl_xor(vpd, off);
            }
            if (fr == 0) { sps[wnIdx][row] = vps; spd[wnIdx][row] = vpd; }
        }
    }
    __syncthreads();
    if (t < 128) {
        int gr = row0 + t;
        if (gr < M) {
            s_src[gr] = sps[0][t] + sps[1][t];
            s_dst[gr] = spd[0][t] + spd[1][t];
        }
    }
    #pragma unroll
    for (int pp = 0; pp < 4; ++pp) {
        int idx = t + pp * 512;
        int row = idx >> 4, seg = idx & 15;
        int gr = row0 + row;
        if (gr < M)
            *(half8*)(hbuf + (size_t)gr * 128 + seg * 8) = *(half8*)&sc[row * 128 + seg * 8];
    }
}

// ---------------- gemm2 fused with MLP head (N=512, 8-wave BK=64, partials out) -----
// R24: A = Y1 single-f16 -> 2-term MFMA.
__global__ __launch_bounds__(512) void k_mgemm_head(
    const _Float16* __restrict__ Ahi,
    const _Float16* __restrict__ Bhi, const _Float16* __restrict__ Blo,
    const float* __restrict__ bias, const float* __restrict__ Wo,
    float* __restrict__ partial,
    int M, int K, int nx, int ntiles)
{
    __shared__ _Float16 sm[3][2][128][32];   // 48 KiB (A, Bhi, Blo)
    __shared__ float4 sacc[2][128];          // 4 KiB: per-wn-half row partials

    int bid = blockIdx.x;
    int per = (ntiles + 7) >> 3;
    int g = (bid & 7) * per + (bid >> 3);
    if (g >= ntiles) return;
    int ct = g % nx;
    int col0 = ct * 128;
    int row0 = (g / nx) * 128;

    phase_stagger(bid);

    int t = threadIdx.x;
    int w = t >> 6, lane = t & 63;
    int wm = (w & 3) * 32, wn = (w >> 2) * 64;   // 8 waves = 4M x 2N
    int fr = lane & 15;
    int fq = lane >> 4, fq8 = fq * 8;

    int srow = t >> 2;
    int scol = (t & 3) << 3;
    int lrow = w << 4;

    f32x4 acc[2][4];
    #pragma unroll
    for (int i = 0; i < 2; i++)
        #pragma unroll
        for (int j = 0; j < 4; j++) acc[i][j] = (f32x4){0.f, 0.f, 0.f, 0.f};

    for (int k0 = 0; k0 < K; k0 += 64) {
        if (k0) __syncthreads();
        {
            int ga = row0 + srow; if (ga > M - 1) ga = M - 1;
            int gb = col0 + srow;
            #pragma unroll
            for (int kk = 0; kk < 2; ++kk) {
                int kc = k0 + kk * 32 + scol;
                gload_lds16(Ahi + (size_t)ga * K + kc, &sm[0][kk][lrow][0]);
                gload_lds16(Bhi + (size_t)gb * K + kc, &sm[1][kk][lrow][0]);
                gload_lds16(Blo + (size_t)gb * K + kc, &sm[2][kk][lrow][0]);
            }
        }
        __syncthreads();

        #pragma unroll
        for (int kk = 0; kk < 2; ++kk) {
            half8 bh[4], bl[4];
            #pragma unroll
            for (int ni = 0; ni < 4; ++ni) {
                bh[ni] = *(half8*)&sm[1][kk][wn + ni * 16 + fr][fq8];
                bl[ni] = *(half8*)&sm[2][kk][wn + ni * 16 + fr][fq8];
            }
            #pragma unroll
            for (int mi = 0; mi < 2; ++mi) {
                half8 ah = *(half8*)&sm[0][kk][wm + mi * 16 + fr][fq8];
                #pragma unroll
                for (int ni = 0; ni < 4; ++ni) {
                    acc[mi][ni] = __builtin_amdgcn_mfma_f32_16x16x32_f16(ah, bh[ni], acc[mi][ni], 0, 0, 0);
                    acc[mi][ni] = __builtin_amdgcn_mfma_f32_16x16x32_f16(ah, bl[ni], acc[mi][ni], 0, 0, 0);
                }
            }
        }
    }

    // epilogue: relu(acc+b2) contracted with Wo -> LDS combine -> partial write
    float bv[4];
    float4 wv[4];
    #pragma unroll
    for (int ni = 0; ni < 4; ++ni) {
        int gc = col0 + wn + ni * 16 + fr;
        bv[ni] = bias[gc];
        wv[ni] = *(const float4*)(Wo + (size_t)gc * 4);
    }
    #pragma unroll
    for (int mi = 0; mi < 2; ++mi) {
        #pragma unroll
        for (int r = 0; r < 4; ++r) {
            int row = wm + mi * 16 + fq * 4 + r;
            float o0 = 0.f, o1 = 0.f, o2 = 0.f, o3 = 0.f;
            #pragma unroll
            for (int ni = 0; ni < 4; ++ni) {
                float v = acc[mi][ni][r] + bv[ni];
                v = (v > 0.f) ? v : 0.f;
                o0 += v * wv[ni].x; o1 += v * wv[ni].y;
                o2 += v * wv[ni].z; o3 += v * wv[ni].w;
            }
            #pragma unroll
            for (int off = 1; off < 16; off <<= 1) {
                o0 += __shfl_xor(o0, off); o1 += __shfl_xor(o1, off);
                o2 += __shfl_xor(o2, off); o3 += __shfl_xor(o3, off);
            }
            if (fr == 0) sacc[w >> 2][row] = (float4){o0, o1, o2, o3};
        }
    }
    __syncthreads();
    if (t < 128) {
        int gr = row0 + t;
        if (gr < M) {
            float4 s0 = sacc[0][t], s1 = sacc[1][t];
            float4 o = (float4){s0.x + s1.x, s0.y + s1.y, s0.z + s1.z, s0.w + s1.w};
            *(float4*)(partial + ((size_t)ct * M + gr) * 4) = o;
        }
    }
}

// ---------------- reduce 4 col-tile partials -> out (adds bo) ----------------
__global__ __launch_bounds__(256) void k_headred(const float* __restrict__ partial,
                                                 const float* __restrict__ bo,
                                                 float* __restrict__ out, int M) {
    int r = blockIdx.x * 256 + threadIdx.x;
    if (r >= M) return;
    float4 a = *(const float4*)(partial + ((size_t)0 * M + r) * 4);
    float4 b = *(const float4*)(partial + ((size_t)1 * M + r) * 4);
    float4 c = *(const float4*)(partial + ((size_t)2 * M + r) * 4);
    float4 d = *(const float4*)(partial + ((size_t)3 * M + r) * 4);
    float4 o;
    o.x = a.x + b.x + c.x + d.x + bo[0];
    o.y = a.y + b.y + c.y + d.y + bo[1];
    o.z = a.z + b.z + c.z + d.z + bo[2];
    o.w = a.w + b.w + c.w + d.w + bo[3];
    *(float4*)(out + (size_t)r * 4) = o;
}

extern "C" void kernel_launch(void* const* d_in, const int* in_sizes, int n_in,
                              void* d_out, int out_size, void* d_ws, size_t ws_size,
                              hipStream_t stream) {
    const float* x    = (const float*)d_in[0];
    const int*   eidx = (const int*)d_in[1];
    const float* cW   = (const float*)d_in[2];
    const float* caS  = (const float*)d_in[3];
    const float* caD  = (const float*)d_in[4];
    const float* cB   = (const float*)d_in[5];
    const float* W0   = (const float*)d_in[6];
    const float* b0   = (const float*)d_in[7];
    const float* W1   = (const float*)d_in[8];
    const float* b1   = (const float*)d_in[9];
    const float* W2   = (const float*)d_in[10];
    const float* b2   = (const float*)d_in[11];
    const float* Wo   = (const float*)d_in[12];
    const float* bo   = (const float*)d_in[13];
    (void)in_sizes; (void)n_in; (void)out_size;

    const int* esrc = eidx;
    const int* edst = eidx + NE;
    float* out = (float*)d_out;

    // ---- workspace bump allocator (256B aligned) ----
    char* w = (char*)d_ws;
    auto alloc = [&](size_t bytes) -> char* {
        char* p = w;
        w += (bytes + 255) & ~(size_t)255;
        return p;
    };
    _Float16* x0h  = (_Float16*)alloc((size_t)NN * 128 * 2);
    _Float16* x0l  = (_Float16*)alloc((size_t)NN * 128 * 2);
    _Float16* xh   = (_Float16*)alloc((size_t)NN * 128 * 2);
    _Float16* hbuf = (_Float16*)alloc((size_t)NN * 128 * 2);   // f16 (R17)
    float* ssrc    = (float*)alloc((size_t)NN * 4);
    float* sdst    = (float*)alloc((size_t)NN * 4);
    int*   counts  = (int*)  alloc((size_t)NN * 4);
    int*   offs    = (int*)  alloc((size_t)(NN + 1) * 4);
    int*   cursor  = (int*)  alloc((size_t)NN * 4);
    int*   csr     = (int*)  alloc((size_t)NET * 4);
    int*   part    = (int*)  alloc((size_t)SCAN_NB * 4);
    _Float16* cwh  = (_Float16*)alloc(3 * 128 * 128 * 2);
    _Float16* cwl  = (_Float16*)alloc(3 * 128 * 128 * 2);
    _Float16* w0h  = (_Float16*)alloc(512 * 128 * 2);
    _Float16* w0l  = (_Float16*)alloc(512 * 128 * 2);
    _Float16* w1h  = (_Float16*)alloc(512 * 512 * 2);
    _Float16* w1l  = (_Float16*)alloc(512 * 512 * 2);
    _Float16* w2h  = (_Float16*)alloc(512 * 512 * 2);
    _Float16* w2l  = (_Float16*)alloc(512 * 512 * 2);
    float* hpart   = (float*)alloc((size_t)4 * NN * 4 * 4);   // head partials [4][NN][4]

    size_t used = (size_t)(w - (char*)d_ws);
    size_t rem = (ws_size > used) ? (ws_size - used) : 0;
    int chunk = (int)(rem / (2 * 512 * sizeof(_Float16)));   // Y0h + Y1h only
    if (chunk > NN) chunk = NN;
    if (chunk > 128) chunk &= ~127;
    if (chunk < 1) chunk = 1;
    _Float16* Y0h = (_Float16*)alloc((size_t)chunk * 512 * 2);
    _Float16* Y1h = (_Float16*)alloc((size_t)chunk * 512 * 2);

    auto gemm = [&](const _Float16* Ah, const _Float16* Al,
                    const _Float16* Bh, const _Float16* Bl,
                    const float* bias, float* Cf, _Float16* Ch, _Float16* Cl,
                    int M, int N, int K, int relu, int split) {
        int nx = N / 128;
        int ntiles = nx * ((M + 127) / 128);
        int nb = ((ntiles + 7) / 8) * 8;
        k_mgemm<<<nb, 512, 0, stream>>>(Ah, Al, Bh, Bl, bias, Cf, Ch, Cl,
                                        M, N, K, relu, split, nx, ntiles);
    };

    // ---- prep: split x, transpose+split weights ----
    k_split<<<2048, 256, 0, stream>>>(x, x0h, x0l, NN * 128);
    for (int L = 0; L < 3; ++L)
        k_prepw<<<dim3(128 / 32, 128 / 32), 256, 0, stream>>>(
            cW + (size_t)L * 128 * 128, cwh + (size_t)L * 128 * 128, cwl + (size_t)L * 128 * 128, 128, 128);
    k_prepw<<<dim3(512 / 32, 128 / 32), 256, 0, stream>>>(W0, w0h, w0l, 128, 512);
    k_prepw<<<dim3(512 / 32, 512 / 32), 256, 0, stream>>>(W1, w1h, w1l, 512, 512);
    k_prepw<<<dim3(512 / 32, 512 / 32), 256, 0, stream>>>(W2, w2h, w2l, 512, 512);

    // ---- build CSR once ----
    hipMemsetAsync(counts, 0, (size_t)NN * 4, stream);
    int eblocks = (NET + 255) / 256;
    k_count <<<eblocks, 256, 0, stream>>>(edst, counts);
    k_scan1 <<<SCAN_NB, 256, 0, stream>>>(counts, part);
    k_scan2 <<<1, 256, 0, stream>>>(part, offs);
    k_scan3 <<<SCAN_NB, 256, 0, stream>>>(counts, part, offs, cursor);
    k_scatter<<<eblocks, 256, 0, stream>>>(esrc, edst, cursor, csr);

    // ---- 3 GAT layers (GEMM fused with attention scalars) ----
    // L0: full x0 split; L1/L2: single-f16 xh (R25).
    int gat_tiles = (NN + 127) / 128;
    int gat_nb = ((gat_tiles + 7) / 8) * 8;
    for (int L = 0; L < 3; ++L) {
        const _Float16* Ah = (L == 0) ? x0h : xh;
        const _Float16* Al = (L == 0) ? x0l : nullptr;
        k_mgemm_gat<<<gat_nb, 512, 0, stream>>>(
            Ah, Al, cwh + (size_t)L * 128 * 128, cwl + (size_t)L * 128 * 128,
            caS + L * 128, caD + L * 128, hbuf, ssrc, sdst, NN, gat_tiles);
        k_aggregate<<<NN / 4, 256, 0, stream>>>(hbuf, ssrc, sdst, offs, csr, cB + L * 128, xh);
    }

    // ---- MLP head (single-f16 activations; gemm2 fused with output head) ----
    for (int m0 = 0; m0 < NN; m0 += chunk) {
        int cm = imin(chunk, NN - m0);
        // gemm0: A = xh (single f16, 2-term), out Y0 hi-only
        gemm(xh + (size_t)m0 * 128, nullptr, w0h, w0l, b0,
             nullptr, Y0h, nullptr, cm, 512, 128, 1, 1);
        // gemm1: A = Y0 (single f16, 2-term), out Y1 hi-only
        gemm(Y0h, nullptr, w1h, w1l, b1, nullptr, Y1h, nullptr, cm, 512, 512, 1, 1);
        int nx = 4;
        int ntiles = nx * ((cm + 127) / 128);
        int nb = ((ntiles + 7) / 8) * 8;
        k_mgemm_head<<<nb, 512, 0, stream>>>(Y1h, w2h, w2l, b2, Wo,
                                             hpart, cm, 512, nx, ntiles);
        k_headred<<<(cm + 255) / 256, 256, 0, stream>>>(hpart, bo, out + (size_t)m0 * 4, cm);
    }
}

// Round 18
// 576.485 us; speedup vs baseline: 1.1129x; 1.0232x over previous
//
#include <hip/hip_runtime.h>
#include <hip/hip_bf16.h>

#define NN 50000
#define NE 800000
#define NET (NE + NN)
#define SCAN_NB ((NN + 255) / 256)   // 196

static inline int imin(int a, int b) { return a < b ? a : b; }

typedef _Float16 half8 __attribute__((ext_vector_type(8)));
typedef _Float16 half2v __attribute__((ext_vector_type(2)));
typedef float f32x4 __attribute__((ext_vector_type(4)));

// ---------------- CSR build (graph constant across layers) ----------------
__global__ void k_count(const int* __restrict__ edst, int* __restrict__ counts) {
    int e = blockIdx.x * blockDim.x + threadIdx.x;
    if (e >= NET) return;
    int d = (e < NE) ? edst[e] : (e - NE);   // self loops appended
    atomicAdd(&counts[d], 1);
}

__global__ __launch_bounds__(256) void k_scan1(const int* __restrict__ counts,
                                               int* __restrict__ part) {
    __shared__ int s[256];
    int t = threadIdx.x, i = blockIdx.x * 256 + t;
    s[t] = (i < NN) ? counts[i] : 0;
    __syncthreads();
    for (int off = 128; off > 0; off >>= 1) {
        if (t < off) s[t] += s[t + off];
        __syncthreads();
    }
    if (t == 0) part[blockIdx.x] = s[0];
}

__global__ __launch_bounds__(256) void k_scan2(int* __restrict__ part, int* __restrict__ offs) {
    __shared__ int s[256];
    int t = threadIdx.x;
    int v = (t < SCAN_NB) ? part[t] : 0;
    s[t] = v;
    __syncthreads();
    for (int off = 1; off < 256; off <<= 1) {
        int a = (t >= off) ? s[t - off] : 0;
        __syncthreads();
        s[t] += a;
        __syncthreads();
    }
    if (t < SCAN_NB) part[t] = s[t] - v;     // exclusive block offsets
    if (t == 255) offs[NN] = s[255];         // total (= NET)
}

__global__ __launch_bounds__(256) void k_scan3(const int* __restrict__ counts,
                                               const int* __restrict__ part,
                                               int* __restrict__ offs, int* __restrict__ cursor) {
    __shared__ int s[256];
    int t = threadIdx.x, i = blockIdx.x * 256 + t;
    int v = (i < NN) ? counts[i] : 0;
    s[t] = v;
    __syncthreads();
    for (int off = 1; off < 256; off <<= 1) {
        int a = (t >= off) ? s[t - off] : 0;
        __syncthreads();
        s[t] += a;
        __syncthreads();
    }
    if (i < NN) {
        int e = part[blockIdx.x] + s[t] - v;
        offs[i] = e;
        cursor[i] = e;
    }
}

__global__ void k_scatter(const int* __restrict__ esrc, const int* __restrict__ edst,
                          int* __restrict__ cursor, int* __restrict__ csr_src) {
    int e = blockIdx.x * blockDim.x + threadIdx.x;
    if (e >= NET) return;
    int s, d;
    if (e < NE) { s = esrc[e]; d = edst[e]; } else { s = e - NE; d = s; }
    int pos = atomicAdd(&cursor[d], 1);
    csr_src[pos] = s;
}

// ---------------- split fp32 -> f16 hi/lo pair ----------------
__global__ void k_split(const float* __restrict__ in, _Float16* __restrict__ hi,
                        _Float16* __restrict__ lo, int n) {
    int i = blockIdx.x * blockDim.x + threadIdx.x;
    int st = gridDim.x * blockDim.x;
    for (; i < n; i += st) {
        float v = in[i];
        _Float16 h = (_Float16)v;
        hi[i] = h;
        lo[i] = (_Float16)(v - (float)h);
    }
}

// ---------------- transpose + split weights: W[K][N] -> T[N][K] hi/lo (LDS-tiled) ----
__global__ __launch_bounds__(256) void k_prepw(const float* __restrict__ W,
                                               _Float16* __restrict__ Th,
                                               _Float16* __restrict__ Tl, int K, int N) {
    __shared__ float tile[32][33];
    int tx = threadIdx.x & 31, ty = threadIdx.x >> 5;
    int n0 = blockIdx.x * 32, k0 = blockIdx.y * 32;
    #pragma unroll
    for (int r = ty; r < 32; r += 8)
        tile[r][tx] = W[(size_t)(k0 + r) * N + n0 + tx];   // coalesced read
    __syncthreads();
    #pragma unroll
    for (int r = ty; r < 32; r += 8) {
        int n = n0 + r, k = k0 + tx;
        float v = tile[tx][r];
        _Float16 h = (_Float16)v;
        Th[(size_t)n * K + k] = h;                          // coalesced 64B segments
        Tl[(size_t)n * K + k] = (_Float16)(v - (float)h);
    }
}

// ---------------- fused segment-softmax + aggregate + bias + leaky ----------------
// R17: hbuf f16. R23: 8-edge unroll. R25: x output hi-only.
__global__ void k_aggregate(const _Float16* __restrict__ h, const float* __restrict__ s_src,
                            const float* __restrict__ s_dst, const int* __restrict__ offs,
                            const int* __restrict__ csr_src, const float* __restrict__ bias,
                            _Float16* __restrict__ xh) {
    int node = blockIdx.x * 4 + (threadIdx.x >> 6);
    int lane = threadIdx.x & 63;
    if (node >= NN) return;
    int p = offs[node], pe = offs[node + 1];
    float sd = s_dst[node];
    float den0 = 0.f, den1 = 0.f;
    float a00 = 0.f, a01 = 0.f, a10 = 0.f, a11 = 0.f;
    for (; p + 8 <= pe; p += 8) {
        int s0 = csr_src[p + 0], s1 = csr_src[p + 1];
        int s2 = csr_src[p + 2], s3 = csr_src[p + 3];
        int s4 = csr_src[p + 4], s5 = csr_src[p + 5];
        int s6 = csr_src[p + 6], s7 = csr_src[p + 7];
        float e0 = s_src[s0] + sd, e1 = s_src[s1] + sd;
        float e2 = s_src[s2] + sd, e3 = s_src[s3] + sd;
        float e4 = s_src[s4] + sd, e5 = s_src[s5] + sd;
        float e6 = s_src[s6] + sd, e7 = s_src[s7] + sd;
        half2v a0 = *((const half2v*)(h + (size_t)s0 * 128) + lane);
        half2v a1 = *((const half2v*)(h + (size_t)s1 * 128) + lane);
        half2v a2 = *((const half2v*)(h + (size_t)s2 * 128) + lane);
        half2v a3 = *((const half2v*)(h + (size_t)s3 * 128) + lane);
        half2v a4 = *((const half2v*)(h + (size_t)s4 * 128) + lane);
        half2v a5 = *((const half2v*)(h + (size_t)s5 * 128) + lane);
        half2v a6 = *((const half2v*)(h + (size_t)s6 * 128) + lane);
        half2v a7 = *((const half2v*)(h + (size_t)s7 * 128) + lane);
        e0 = (e0 > 0.f) ? e0 : 0.2f * e0;  float w0 = __expf(e0);
        e1 = (e1 > 0.f) ? e1 : 0.2f * e1;  float w1 = __expf(e1);
        e2 = (e2 > 0.f) ? e2 : 0.2f * e2;  float w2 = __expf(e2);
        e3 = (e3 > 0.f) ? e3 : 0.2f * e3;  float w3 = __expf(e3);
        e4 = (e4 > 0.f) ? e4 : 0.2f * e4;  float w4 = __expf(e4);
        e5 = (e5 > 0.f) ? e5 : 0.2f * e5;  float w5 = __expf(e5);
        e6 = (e6 > 0.f) ? e6 : 0.2f * e6;  float w6 = __expf(e6);
        e7 = (e7 > 0.f) ? e7 : 0.2f * e7;  float w7 = __expf(e7);
        den0 += (w0 + w1) + (w2 + w3);
        den1 += (w4 + w5) + (w6 + w7);
        a00 += w0 * (float)a0[0] + w1 * (float)a1[0] + w2 * (float)a2[0] + w3 * (float)a3[0];
        a01 += w0 * (float)a0[1] + w1 * (float)a1[1] + w2 * (float)a2[1] + w3 * (float)a3[1];
        a10 += w4 * (float)a4[0] + w5 * (float)a5[0] + w6 * (float)a6[0] + w7 * (float)a7[0];
        a11 += w4 * (float)a4[1] + w5 * (float)a5[1] + w6 * (float)a6[1] + w7 * (float)a7[1];
    }
    for (; p + 4 <= pe; p += 4) {
        int s0 = csr_src[p + 0], s1 = csr_src[p + 1];
        int s2 = csr_src[p + 2], s3 = csr_src[p + 3];
        float e0 = s_src[s0] + sd, e1 = s_src[s1] + sd;
        float e2 = s_src[s2] + sd, e3 = s_src[s3] + sd;
        half2v a0 = *((const half2v*)(h + (size_t)s0 * 128) + lane);
        half2v a1 = *((const half2v*)(h + (size_t)s1 * 128) + lane);
        half2v a2 = *((const half2v*)(h + (size_t)s2 * 128) + lane);
        half2v a3 = *((const half2v*)(h + (size_t)s3 * 128) + lane);
        e0 = (e0 > 0.f) ? e0 : 0.2f * e0;  float w0 = __expf(e0);
        e1 = (e1 > 0.f) ? e1 : 0.2f * e1;  float w1 = __expf(e1);
        e2 = (e2 > 0.f) ? e2 : 0.2f * e2;  float w2 = __expf(e2);
        e3 = (e3 > 0.f) ? e3 : 0.2f * e3;  float w3 = __expf(e3);
        den0 += (w0 + w1) + (w2 + w3);
        a00 += w0 * (float)a0[0] + w1 * (float)a1[0] + w2 * (float)a2[0] + w3 * (float)a3[0];
        a01 += w0 * (float)a0[1] + w1 * (float)a1[1] + w2 * (float)a2[1] + w3 * (float)a3[1];
    }
    for (; p < pe; ++p) {
        int src = csr_src[p];
        float e = s_src[src] + sd;
        e = (e > 0.f) ? e : 0.2f * e;
        float wgt = __expf(e);
        den0 += wgt;
        half2v av = *((const half2v*)(h + (size_t)src * 128) + lane);
        a00 += wgt * (float)av[0];
        a01 += wgt * (float)av[1];
    }
    float den = den0 + den1;
    float acc0 = a00 + a10, acc1 = a01 + a11;
    float inv = 1.f / den;                    // self-loop guarantees den > 0
    float2 bv = *((const float2*)bias + lane);
    float v0 = acc0 * inv + bv.x;
    float v1 = acc1 * inv + bv.y;
    v0 = (v0 > 0.f) ? v0 : 0.2f * v0;
    v1 = (v1 > 0.f) ? v1 : 0.2f * v1;
    size_t base = (size_t)node * 128 + 2 * lane;
    *(half2v*)(xh + base) = (half2v){(_Float16)v0, (_Float16)v1};
}

// ---------------- shared GEMM machinery ----------
// R26: R16's A-side work cut was NULL -> GAT/MLP GEMMs are LATENCY-bound;
// residency is the currency (R18's +50% waves was the biggest GEMM win).
// k_mgemm still allocated sm[4] (64KB) with sm[1] dead since all call sites
// are 2-term -> 16KB dead LDS capping residency at 2 blk/CU. Fix: 3-array
// 48KB k_mgemm (2-term only) and k_mgemm_gat2 (3-array) for GAT L1/L2;
// L0 keeps 4-array 3-term. No math/schedule changes.
__device__ __forceinline__ void gload_lds16(const void* g, void* l) {
    __builtin_amdgcn_global_load_lds(
        (const __attribute__((address_space(1))) void*)g,
        (__attribute__((address_space(3))) void*)l, 16, 0, 0);
}

// per-block phase stagger: hash(bid) -> 0..7 sleeps of ~512cy. ~free, tiny win.
__device__ __forceinline__ void phase_stagger(int bid) {
    int ph = (int)(((unsigned)bid * 2654435761u) >> 29);
    for (int i = 0; i < ph; ++i) __builtin_amdgcn_s_sleep(8);
}

// ---------------- 2-term split-weight MFMA GEMM (8-wave, BK=64, 48KB LDS) ----
// A single-f16; B split hi/lo. Clo == nullptr -> hi-only out.
__global__ __launch_bounds__(512) void k_mgemm(
    const _Float16* __restrict__ Ahi,
    const _Float16* __restrict__ Bhi, const _Float16* __restrict__ Blo,
    const float* __restrict__ bias,
    _Float16* __restrict__ Chi, _Float16* __restrict__ Clo,
    int M, int N, int K, int relu, int nx, int ntiles)
{
    __shared__ _Float16 sm[3][2][128][32];   // 48 KiB: A, Bhi, Blo; reused as C tile

    int bid = blockIdx.x;
    int per = (ntiles + 7) >> 3;
    int g = (bid & 7) * per + (bid >> 3);
    if (g >= ntiles) return;
    int col0 = (g % nx) * 128;
    int row0 = (g / nx) * 128;

    phase_stagger(bid);

    int t = threadIdx.x;
    int w = t >> 6, lane = t & 63;
    int wm = (w & 3) * 32, wn = (w >> 2) * 64;   // 8 waves = 4M x 2N, wave tile 32x64
    int fr = lane & 15;
    int fq = lane >> 4, fq8 = fq * 8;

    int srow = t >> 2;                // 0..127
    int scol = (t & 3) << 3;          // halfs
    int lrow = w << 4;                // wave-uniform LDS base row

    f32x4 acc[2][4];
    #pragma unroll
    for (int i = 0; i < 2; i++)
        #pragma unroll
        for (int j = 0; j < 4; j++) acc[i][j] = (f32x4){0.f, 0.f, 0.f, 0.f};

    for (int k0 = 0; k0 < K; k0 += 64) {
        if (k0) __syncthreads();
        {
            int ga = row0 + srow; if (ga > M - 1) ga = M - 1;  // M-tail: dup reads, guarded at store
            int gb = col0 + srow;                               // N % 128 == 0 -> in range
            #pragma unroll
            for (int kk = 0; kk < 2; ++kk) {
                int kc = k0 + kk * 32 + scol;
                gload_lds16(Ahi + (size_t)ga * K + kc, &sm[0][kk][lrow][0]);
                gload_lds16(Bhi + (size_t)gb * K + kc, &sm[1][kk][lrow][0]);
                gload_lds16(Blo + (size_t)gb * K + kc, &sm[2][kk][lrow][0]);
            }
        }
        __syncthreads();   // drains vmcnt -> gload_lds stores visible to all waves

        #pragma unroll
        for (int kk = 0; kk < 2; ++kk) {
            half8 bh[4], bl[4];
            #pragma unroll
            for (int ni = 0; ni < 4; ++ni) {
                bh[ni] = *(half8*)&sm[1][kk][wn + ni * 16 + fr][fq8];
                bl[ni] = *(half8*)&sm[2][kk][wn + ni * 16 + fr][fq8];
            }
            #pragma unroll
            for (int mi = 0; mi < 2; ++mi) {
                half8 ah = *(half8*)&sm[0][kk][wm + mi * 16 + fr][fq8];
                #pragma unroll
                for (int ni = 0; ni < 4; ++ni) {
                    acc[mi][ni] = __builtin_amdgcn_mfma_f32_16x16x32_f16(ah, bh[ni], acc[mi][ni], 0, 0, 0);
                    acc[mi][ni] = __builtin_amdgcn_mfma_f32_16x16x32_f16(ah, bl[ni], acc[mi][ni], 0, 0, 0);
                }
            }
        }
    }

    float bv[4];
    #pragma unroll
    for (int ni = 0; ni < 4; ++ni)
        bv[ni] = bias ? bias[col0 + wn + ni * 16 + fr] : 0.f;

    // R19 epilogue: restage C via LDS -> 16B coalesced stores.
    _Float16* sc = &sm[0][0][0][0];   // [128][128] overlay (32 KiB of 48)
    int npass = Clo ? 2 : 1;
    for (int pass = 0; pass < npass; ++pass) {
        __syncthreads();
        #pragma unroll
        for (int mi = 0; mi < 2; ++mi) {
            #pragma unroll
            for (int ni = 0; ni < 4; ++ni) {
                #pragma unroll
                for (int r = 0; r < 4; ++r) {
                    int row = wm + mi * 16 + fq * 4 + r;
                    int col = wn + ni * 16 + fr;
                    float v = acc[mi][ni][r] + bv[ni];
                    if (relu) v = (v > 0.f) ? v : 0.f;
                    _Float16 hh = (_Float16)v;
                    sc[row * 128 + col] = pass ? (_Float16)(v - (float)hh) : hh;
                }
            }
        }
        __syncthreads();
        _Float16* dst = pass ? Clo : Chi;
        #pragma unroll
        for (int pp = 0; pp < 4; ++pp) {
            int idx = t + pp * 512;
            int row = idx >> 4, seg = idx & 15;
            int gr = row0 + row;
            if (gr < M)
                *(half8*)(dst + (size_t)gr * N + col0 + seg * 8) =
                    *(half8*)&sc[row * 128 + seg * 8];
        }
    }
}

// ---------------- GAT GEMM L0: 3-term, 4-array 64KB (full x0 split) ----------------
__global__ __launch_bounds__(512) void k_mgemm_gat(
    const _Float16* __restrict__ Ahi, const _Float16* __restrict__ Alo,
    const _Float16* __restrict__ Bhi, const _Float16* __restrict__ Blo,
    const float* __restrict__ a_src, const float* __restrict__ a_dst,
    _Float16* __restrict__ hbuf, float* __restrict__ s_src, float* __restrict__ s_dst,
    int M, int ntiles)
{
    __shared__ _Float16 sm[4][2][128][32];   // 64 KiB; reused as hbuf C tile
    __shared__ float sps[2][128], spd[2][128];

    const int K = 128;
    int bid = blockIdx.x;
    int per = (ntiles + 7) >> 3;
    int g = (bid & 7) * per + (bid >> 3);
    if (g >= ntiles) return;
    int row0 = g * 128;                    // nx == 1 (N = 128)

    int t = threadIdx.x;
    int w = t >> 6, lane = t & 63;
    int wm = (w & 3) * 32, wn = (w >> 2) * 64;   // 8 waves = 4M x 2N
    int fr = lane & 15;
    int fq = lane >> 4, fq8 = fq * 8;
    int wnIdx = w >> 2;

    int srow = t >> 2;
    int scol = (t & 3) << 3;
    int lrow = w << 4;

    f32x4 acc[2][4];
    #pragma unroll
    for (int i = 0; i < 2; i++)
        #pragma unroll
        for (int j = 0; j < 4; j++) acc[i][j] = (f32x4){0.f, 0.f, 0.f, 0.f};

    for (int k0 = 0; k0 < K; k0 += 64) {
        if (k0) __syncthreads();
        {
            int ga = row0 + srow; if (ga > M - 1) ga = M - 1;
            int gb = srow;                                    // col0 = 0, N = 128
            #pragma unroll
            for (int kk = 0; kk < 2; ++kk) {
                int kc = k0 + kk * 32 + scol;
                gload_lds16(Ahi + (size_t)ga * K + kc, &sm[0][kk][lrow][0]);
                gload_lds16(Alo + (size_t)ga * K + kc, &sm[1][kk][lrow][0]);
                gload_lds16(Bhi + (size_t)gb * K + kc, &sm[2][kk][lrow][0]);
                gload_lds16(Blo + (size_t)gb * K + kc, &sm[3][kk][lrow][0]);
            }
        }
        __syncthreads();

        #pragma unroll
        for (int kk = 0; kk < 2; ++kk) {
            half8 bh[4], bl[4];
            #pragma unroll
            for (int ni = 0; ni < 4; ++ni) {
                bh[ni] = *(half8*)&sm[2][kk][wn + ni * 16 + fr][fq8];
                bl[ni] = *(half8*)&sm[3][kk][wn + ni * 16 + fr][fq8];
            }
            #pragma unroll
            for (int mi = 0; mi < 2; ++mi) {
                half8 ah = *(half8*)&sm[0][kk][wm + mi * 16 + fr][fq8];
                half8 al = *(half8*)&sm[1][kk][wm + mi * 16 + fr][fq8];
                #pragma unroll
                for (int ni = 0; ni < 4; ++ni) {
                    acc[mi][ni] = __builtin_amdgcn_mfma_f32_16x16x32_f16(ah, bh[ni], acc[mi][ni], 0, 0, 0);
                    acc[mi][ni] = __builtin_amdgcn_mfma_f32_16x16x32_f16(ah, bl[ni], acc[mi][ni], 0, 0, 0);
                    acc[mi][ni] = __builtin_amdgcn_mfma_f32_16x16x32_f16(al, bh[ni], acc[mi][ni], 0, 0, 0);
                }
            }
        }
    }

    // epilogue: scalar dots + restage hbuf via LDS
    float asv[4], adv[4];
    #pragma unroll
    for (int ni = 0; ni < 4; ++ni) {
        int gc = wn + ni * 16 + fr;
        asv[ni] = a_src[gc];
        adv[ni] = a_dst[gc];
    }
    __syncthreads();
    _Float16* sc = &sm[0][0][0][0];   // [128][128]
    #pragma unroll
    for (int mi = 0; mi < 2; ++mi) {
        #pragma unroll
        for (int r = 0; r < 4; ++r) {
            int row = wm + mi * 16 + fq * 4 + r;
            float vps = 0.f, vpd = 0.f;
            #pragma unroll
            for (int ni = 0; ni < 4; ++ni) {
                float v = acc[mi][ni][r];
                vps += v * asv[ni];
                vpd += v * adv[ni];
                sc[row * 128 + wn + ni * 16 + fr] = (_Float16)v;
            }
            #pragma unroll
            for (int off = 1; off < 16; off <<= 1) {
                vps += __shfl_xor(vps, off);
                vpd += __shfl_xor(vpd, off);
            }
            if (fr == 0) { sps[wnIdx][row] = vps; spd[wnIdx][row] = vpd; }
        }
    }
    __syncthreads();
    if (t < 128) {
        int gr = row0 + t;
        if (gr < M) {
            s_src[gr] = sps[0][t] + sps[1][t];
            s_dst[gr] = spd[0][t] + spd[1][t];
        }
    }
    #pragma unroll
    for (int pp = 0; pp < 4; ++pp) {
        int idx = t + pp * 512;
        int row = idx >> 4, seg = idx & 15;
        int gr = row0 + row;
        if (gr < M)
            *(half8*)(hbuf + (size_t)gr * 128 + seg * 8) = *(half8*)&sc[row * 128 + seg * 8];
    }
}

// ---------------- GAT GEMM L1/L2: 2-term, 3-array 48KB (R26) ----------------
__global__ __launch_bounds__(512) void k_mgemm_gat2(
    const _Float16* __restrict__ Ahi,
    const _Float16* __restrict__ Bhi, const _Float16* __restrict__ Blo,
    const float* __restrict__ a_src, const float* __restrict__ a_dst,
    _Float16* __restrict__ hbuf, float* __restrict__ s_src, float* __restrict__ s_dst,
    int M, int ntiles)
{
    __shared__ _Float16 sm[3][2][128][32];   // 48 KiB; reused as hbuf C tile
    __shared__ float sps[2][128], spd[2][128];

    const int K = 128;
    int bid = blockIdx.x;
    int per = (ntiles + 7) >> 3;
    int g = (bid & 7) * per + (bid >> 3);
    if (g >= ntiles) return;
    int row0 = g * 128;                    // nx == 1 (N = 128)

    int t = threadIdx.x;
    int w = t >> 6, lane = t & 63;
    int wm = (w & 3) * 32, wn = (w >> 2) * 64;   // 8 waves = 4M x 2N
    int fr = lane & 15;
    int fq = lane >> 4, fq8 = fq * 8;
    int wnIdx = w >> 2;

    int srow = t >> 2;
    int scol = (t & 3) << 3;
    int lrow = w << 4;

    f32x4 acc[2][4];
    #pragma unroll
    for (int i = 0; i < 2; i++)
        #pragma unroll
        for (int j = 0; j < 4; j++) acc[i][j] = (f32x4){0.f, 0.f, 0.f, 0.f};

    for (int k0 = 0; k0 < K; k0 += 64) {
        if (k0) __syncthreads();
        {
            int ga = row0 + srow; if (ga > M - 1) ga = M - 1;
            int gb = srow;                                    // col0 = 0, N = 128
            #pragma unroll
            for (int kk = 0; kk < 2; ++kk) {
                int kc = k0 + kk * 32 + scol;
                gload_lds16(Ahi + (size_t)ga * K + kc, &sm[0][kk][lrow][0]);
                gload_lds16(Bhi + (size_t)gb * K + kc, &sm[1][kk][lrow][0]);
                gload_lds16(Blo + (size_t)gb * K + kc, &sm[2][kk][lrow][0]);
            }
        }
        __syncthreads();

        #pragma unroll
        for (int kk = 0; kk < 2; ++kk) {
            half8 bh[4], bl[4];
            #pragma unroll
            for (int ni = 0; ni < 4; ++ni) {
                bh[ni] = *(half8*)&sm[1][kk][wn + ni * 16 + fr][fq8];
                bl[ni] = *(half8*)&sm[2][kk][wn + ni * 16 + fr][fq8];
            }
            #pragma unroll
            for (int mi = 0; mi < 2; ++mi) {
                half8 ah = *(half8*)&sm[0][kk][wm + mi * 16 + fr][fq8];
                #pragma unroll
                for (int ni = 0; ni < 4; ++ni) {
                    acc[mi][ni] = __builtin_amdgcn_mfma_f32_16x16x32_f16(ah, bh[ni], acc[mi][ni], 0, 0, 0);
                    acc[mi][ni] = __builtin_amdgcn_mfma_f32_16x16x32_f16(ah, bl[ni], acc[mi][ni], 0, 0, 0);
                }
            }
        }
    }

    // epilogue: scalar dots + restage hbuf via LDS
    float asv[4], adv[4];
    #pragma unroll
    for (int ni = 0; ni < 4; ++ni) {
        int gc = wn + ni * 16 + fr;
        asv[ni] = a_src[gc];
        adv[ni] = a_dst[gc];
    }
    __syncthreads();
    _Float16* sc = &sm[0][0][0][0];   // [128][128]
    #pragma unroll
    for (int mi = 0; mi < 2; ++mi) {
        #pragma unroll
        for (int r = 0; r < 4; ++r) {
            int row = wm + mi * 16 + fq * 4 + r;
            float vps = 0.f, vpd = 0.f;
            #pragma unroll
            for (int ni = 0; ni < 4; ++ni) {
                float v = acc[mi][ni][r];
                vps += v * asv[ni];
                vpd += v * adv[ni];
                sc[row * 128 + wn + ni * 16 + fr] = (_Float16)v;
            }
            #pragma unroll
            for (int off = 1; off < 16; off <<= 1) {
                vps += __shfl_xor(vps, off);
                vpd += __shfl_xor(vpd, off);
            }
            if (fr == 0) { sps[wnIdx][row] = vps; spd[wnIdx][row] = vpd; }
        }
    }
    __syncthreads();
    if (t < 128) {
        int gr = row0 + t;
        if (gr < M) {
            s_src[gr] = sps[0][t] + sps[1][t];
            s_dst[gr] = spd[0][t] + spd[1][t];
        }
    }
    #pragma unroll
    for (int pp = 0; pp < 4; ++pp) {
        int idx = t + pp * 512;
        int row = idx >> 4, seg = idx & 15;
        int gr = row0 + row;
        if (gr < M)
            *(half8*)(hbuf + (size_t)gr * 128 + seg * 8) = *(half8*)&sc[row * 128 + seg * 8];
    }
}

// ---------------- gemm2 fused with MLP head (N=512, 8-wave BK=64, partials out) -----
__global__ __launch_bounds__(512) void k_mgemm_head(
    const _Float16* __restrict__ Ahi,
    const _Float16* __restrict__ Bhi, const _Float16* __restrict__ Blo,
    const float* __restrict__ bias, const float* __restrict__ Wo,
    float* __restrict__ partial,
    int M, int K, int nx, int ntiles)
{
    __shared__ _Float16 sm[3][2][128][32];   // 48 KiB (A, Bhi, Blo)
    __shared__ float4 sacc[2][128];          // 4 KiB: per-wn-half row partials

    int bid = blockIdx.x;
    int per = (ntiles + 7) >> 3;
    int g = (bid & 7) * per + (bid >> 3);
    if (g >= ntiles) return;
    int ct = g % nx;
    int col0 = ct * 128;
    int row0 = (g / nx) * 128;

    phase_stagger(bid);

    int t = threadIdx.x;
    int w = t >> 6, lane = t & 63;
    int wm = (w & 3) * 32, wn = (w >> 2) * 64;   // 8 waves = 4M x 2N
    int fr = lane & 15;
    int fq = lane >> 4, fq8 = fq * 8;

    int srow = t >> 2;
    int scol = (t & 3) << 3;
    int lrow = w << 4;

    f32x4 acc[2][4];
    #pragma unroll
    for (int i = 0; i < 2; i++)
        #pragma unroll
        for (int j = 0; j < 4; j++) acc[i][j] = (f32x4){0.f, 0.f, 0.f, 0.f};

    for (int k0 = 0; k0 < K; k0 += 64) {
        if (k0) __syncthreads();
        {
            int ga = row0 + srow; if (ga > M - 1) ga = M - 1;
            int gb = col0 + srow;
            #pragma unroll
            for (int kk = 0; kk < 2; ++kk) {
                int kc = k0 + kk * 32 + scol;
                gload_lds16(Ahi + (size_t)ga * K + kc, &sm[0][kk][lrow][0]);
                gload_lds16(Bhi + (size_t)gb * K + kc, &sm[1][kk][lrow][0]);
                gload_lds16(Blo + (size_t)gb * K + kc, &sm[2][kk][lrow][0]);
            }
        }
        __syncthreads();

        #pragma unroll
        for (int kk = 0; kk < 2; ++kk) {
            half8 bh[4], bl[4];
            #pragma unroll
            for (int ni = 0; ni < 4; ++ni) {
                bh[ni] = *(half8*)&sm[1][kk][wn + ni * 16 + fr][fq8];
                bl[ni] = *(half8*)&sm[2][kk][wn + ni * 16 + fr][fq8];
            }
            #pragma unroll
            for (int mi = 0; mi < 2; ++mi) {
                half8 ah = *(half8*)&sm[0][kk][wm + mi * 16 + fr][fq8];
                #pragma unroll
                for (int ni = 0; ni < 4; ++ni) {
                    acc[mi][ni] = __builtin_amdgcn_mfma_f32_16x16x32_f16(ah, bh[ni], acc[mi][ni], 0, 0, 0);
                    acc[mi][ni] = __builtin_amdgcn_mfma_f32_16x16x32_f16(ah, bl[ni], acc[mi][ni], 0, 0, 0);
                }
            }
        }
    }

    // epilogue: relu(acc+b2) contracted with Wo -> LDS combine -> partial write
    float bv[4];
    float4 wv[4];
    #pragma unroll
    for (int ni = 0; ni < 4; ++ni) {
        int gc = col0 + wn + ni * 16 + fr;
        bv[ni] = bias[gc];
        wv[ni] = *(const float4*)(Wo + (size_t)gc * 4);
    }
    #pragma unroll
    for (int mi = 0; mi < 2; ++mi) {
        #pragma unroll
        for (int r = 0; r < 4; ++r) {
            int row = wm + mi * 16 + fq * 4 + r;
            float o0 = 0.f, o1 = 0.f, o2 = 0.f, o3 = 0.f;
            #pragma unroll
            for (int ni = 0; ni < 4; ++ni) {
                float v = acc[mi][ni][r] + bv[ni];
                v = (v > 0.f) ? v : 0.f;
                o0 += v * wv[ni].x; o1 += v * wv[ni].y;
                o2 += v * wv[ni].z; o3 += v * wv[ni].w;
            }
            #pragma unroll
            for (int off = 1; off < 16; off <<= 1) {
                o0 += __shfl_xor(o0, off); o1 += __shfl_xor(o1, off);
                o2 += __shfl_xor(o2, off); o3 += __shfl_xor(o3, off);
            }
            if (fr == 0) sacc[w >> 2][row] = (float4){o0, o1, o2, o3};
        }
    }
    __syncthreads();
    if (t < 128) {
        int gr = row0 + t;
        if (gr < M) {
            float4 s0 = sacc[0][t], s1 = sacc[1][t];
            float4 o = (float4){s0.x + s1.x, s0.y + s1.y, s0.z + s1.z, s0.w + s1.w};
            *(float4*)(partial + ((size_t)ct * M + gr) * 4) = o;
        }
    }
}

// ---------------- reduce 4 col-tile partials -> out (adds bo) ----------------
__global__ __launch_bounds__(256) void k_headred(const float* __restrict__ partial,
                                                 const float* __restrict__ bo,
                                                 float* __restrict__ out, int M) {
    int r = blockIdx.x * 256 + threadIdx.x;
    if (r >= M) return;
    float4 a = *(const float4*)(partial + ((size_t)0 * M + r) * 4);
    float4 b = *(const float4*)(partial + ((size_t)1 * M + r) * 4);
    float4 c = *(const float4*)(partial + ((size_t)2 * M + r) * 4);
    float4 d = *(const float4*)(partial + ((size_t)3 * M + r) * 4);
    float4 o;
    o.x = a.x + b.x + c.x + d.x + bo[0];
    o.y = a.y + b.y + c.y + d.y + bo[1];
    o.z = a.z + b.z + c.z + d.z + bo[2];
    o.w = a.w + b.w + c.w + d.w + bo[3];
    *(float4*)(out + (size_t)r * 4) = o;
}

extern "C" void kernel_launch(void* const* d_in, const int* in_sizes, int n_in,
                              void* d_out, int out_size, void* d_ws, size_t ws_size,
                              hipStream_t stream) {
    const float* x    = (const float*)d_in[0];
    const int*   eidx = (const int*)d_in[1];
    const float* cW   = (const float*)d_in[2];
    const float* caS  = (const float*)d_in[3];
    const float* caD  = (const float*)d_in[4];
    const float* cB   = (const float*)d_in[5];
    const float* W0   = (const float*)d_in[6];
    const float* b0   = (const float*)d_in[7];
    const float* W1   = (const float*)d_in[8];
    const float* b1   = (const float*)d_in[9];
    const float* W2   = (const float*)d_in[10];
    const float* b2   = (const float*)d_in[11];
    const float* Wo   = (const float*)d_in[12];
    const float* bo   = (const float*)d_in[13];
    (void)in_sizes; (void)n_in; (void)out_size;

    const int* esrc = eidx;
    const int* edst = eidx + NE;
    float* out = (float*)d_out;

    // ---- workspace bump allocator (256B aligned) ----
    char* w = (char*)d_ws;
    auto alloc = [&](size_t bytes) -> char* {
        char* p = w;
        w += (bytes + 255) & ~(size_t)255;
        return p;
    };
    _Float16* x0h  = (_Float16*)alloc((size_t)NN * 128 * 2);
    _Float16* x0l  = (_Float16*)alloc((size_t)NN * 128 * 2);
    _Float16* xh   = (_Float16*)alloc((size_t)NN * 128 * 2);
    _Float16* hbuf = (_Float16*)alloc((size_t)NN * 128 * 2);   // f16 (R17)
    float* ssrc    = (float*)alloc((size_t)NN * 4);
    float* sdst    = (float*)alloc((size_t)NN * 4);
    int*   counts  = (int*)  alloc((size_t)NN * 4);
    int*   offs    = (int*)  alloc((size_t)(NN + 1) * 4);
    int*   cursor  = (int*)  alloc((size_t)NN * 4);
    int*   csr     = (int*)  alloc((size_t)NET * 4);
    int*   part    = (int*)  alloc((size_t)SCAN_NB * 4);
    _Float16* cwh  = (_Float16*)alloc(3 * 128 * 128 * 2);
    _Float16* cwl  = (_Float16*)alloc(3 * 128 * 128 * 2);
    _Float16* w0h  = (_Float16*)alloc(512 * 128 * 2);
    _Float16* w0l  = (_Float16*)alloc(512 * 128 * 2);
    _Float16* w1h  = (_Float16*)alloc(512 * 512 * 2);
    _Float16* w1l  = (_Float16*)alloc(512 * 512 * 2);
    _Float16* w2h  = (_Float16*)alloc(512 * 512 * 2);
    _Float16* w2l  = (_Float16*)alloc(512 * 512 * 2);
    float* hpart   = (float*)alloc((size_t)4 * NN * 4 * 4);   // head partials [4][NN][4]

    size_t used = (size_t)(w - (char*)d_ws);
    size_t rem = (ws_size > used) ? (ws_size - used) : 0;
    int chunk = (int)(rem / (2 * 512 * sizeof(_Float16)));   // Y0h + Y1h only
    if (chunk > NN) chunk = NN;
    if (chunk > 128) chunk &= ~127;
    if (chunk < 1) chunk = 1;
    _Float16* Y0h = (_Float16*)alloc((size_t)chunk * 512 * 2);
    _Float16* Y1h = (_Float16*)alloc((size_t)chunk * 512 * 2);

    auto gemm = [&](const _Float16* Ah,
                    const _Float16* Bh, const _Float16* Bl,
                    const float* bias, _Float16* Ch, _Float16* Cl,
                    int M, int N, int K, int relu) {
        int nx = N / 128;
        int ntiles = nx * ((M + 127) / 128);
        int nb = ((ntiles + 7) / 8) * 8;
        k_mgemm<<<nb, 512, 0, stream>>>(Ah, Bh, Bl, bias, Ch, Cl,
                                        M, N, K, relu, nx, ntiles);
    };

    // ---- prep: split x, transpose+split weights ----
    k_split<<<2048, 256, 0, stream>>>(x, x0h, x0l, NN * 128);
    for (int L = 0; L < 3; ++L)
        k_prepw<<<dim3(128 / 32, 128 / 32), 256, 0, stream>>>(
            cW + (size_t)L * 128 * 128, cwh + (size_t)L * 128 * 128, cwl + (size_t)L * 128 * 128, 128, 128);
    k_prepw<<<dim3(512 / 32, 128 / 32), 256, 0, stream>>>(W0, w0h, w0l, 128, 512);
    k_prepw<<<dim3(512 / 32, 512 / 32), 256, 0, stream>>>(W1, w1h, w1l, 512, 512);
    k_prepw<<<dim3(512 / 32, 512 / 32), 256, 0, stream>>>(W2, w2h, w2l, 512, 512);

    // ---- build CSR once ----
    hipMemsetAsync(counts, 0, (size_t)NN * 4, stream);
    int eblocks = (NET + 255) / 256;
    k_count <<<eblocks, 256, 0, stream>>>(edst, counts);
    k_scan1 <<<SCAN_NB, 256, 0, stream>>>(counts, part);
    k_scan2 <<<1, 256, 0, stream>>>(part, offs);
    k_scan3 <<<SCAN_NB, 256, 0, stream>>>(counts, part, offs, cursor);
    k_scatter<<<eblocks, 256, 0, stream>>>(esrc, edst, cursor, csr);

    // ---- 3 GAT layers ----
    // L0: 4-array 3-term (full x0 split); L1/L2: 3-array 2-term (R26).
    int gat_tiles = (NN + 127) / 128;
    int gat_nb = ((gat_tiles + 7) / 8) * 8;
    for (int L = 0; L < 3; ++L) {
        if (L == 0)
            k_mgemm_gat<<<gat_nb, 512, 0, stream>>>(
                x0h, x0l, cwh + (size_t)L * 128 * 128, cwl + (size_t)L * 128 * 128,
                caS + L * 128, caD + L * 128, hbuf, ssrc, sdst, NN, gat_tiles);
        else
            k_mgemm_gat2<<<gat_nb, 512, 0, stream>>>(
                xh, cwh + (size_t)L * 128 * 128, cwl + (size_t)L * 128 * 128,
                caS + L * 128, caD + L * 128, hbuf, ssrc, sdst, NN, gat_tiles);
        k_aggregate<<<NN / 4, 256, 0, stream>>>(hbuf, ssrc, sdst, offs, csr, cB + L * 128, xh);
    }

    // ---- MLP head (single-f16 activations; gemm2 fused with output head) ----
    for (int m0 = 0; m0 < NN; m0 += chunk) {
        int cm = imin(chunk, NN - m0);
        gemm(xh + (size_t)m0 * 128, w0h, w0l, b0, Y0h, nullptr, cm, 512, 128, 1);
        gemm(Y0h, w1h, w1l, b1, Y1h, nullptr, cm, 512, 512, 1);
        int nx = 4;
        int ntiles = nx * ((cm + 127) / 128);
        int nb = ((ntiles + 7) / 8) * 8;
        k_mgemm_head<<<nb, 512, 0, stream>>>(Y1h, w2h, w2l, b2, Wo,
                                             hpart, cm, 512, nx, ntiles);
        k_headred<<<(cm + 255) / 256, 256, 0, stream>>>(hpart, bo, out + (size_t)m0 * 4, cm);
    }
}